// Round 17
// baseline (106.348 us; speedup 1.0000x reference)
//
#include <hip/hip_runtime.h>
#include <hip/hip_bf16.h>
#include <math.h>

typedef __attribute__((ext_vector_type(8))) short short8;
typedef __attribute__((ext_vector_type(4))) float f32x4;
typedef unsigned short u16;

static __device__ __forceinline__ u16 f2bf(float f) {
  union { float f; unsigned u; } v; v.f = f;
  unsigned r = v.u + 0x7fffu + ((v.u >> 16) & 1u);
  return (u16)(r >> 16);
}

static __device__ __forceinline__ float bf2f(u16 h) {
  union { unsigned u; float f; } v; v.u = ((unsigned)h) << 16;
  return v.f;
}

// gfx950 HW packed f32->bf16 convert (no builtin; inline asm per T12)
static __device__ __forceinline__ unsigned cvt_pk_bf16(float lo, float hi) {
  unsigned r;
  asm("v_cvt_pk_bf16_f32 %0, %1, %2" : "=v"(r) : "v"(lo), "v"(hi));
  return r;
}

static __device__ __forceinline__ void gload_lds16(const void* g, void* l) {
  __builtin_amdgcn_global_load_lds(
      (const __attribute__((address_space(1))) void*)g,
      (__attribute__((address_space(3))) void*)l, 16, 0, 0);
}

// -------- fused prologue: cvt x -> bf16 | transpose w_attn | transpose w_proj --
__device__ __forceinline__ void transpose_tile(const float* __restrict__ W,
                                               u16* __restrict__ WT,
                                               int ND, int KD, int c0, int k0,
                                               float (*tile)[65], int t) {
  const int lr = t >> 2;
  const int lc = (t & 3) * 16;
  const float* src = W + (size_t)(k0 + lr) * ND + c0 + lc;
#pragma unroll
  for (int i = 0; i < 16; i += 4) {
    float4 v = *(const float4*)(src + i);
    tile[lr][lc + i] = v.x; tile[lr][lc + i + 1] = v.y;
    tile[lr][lc + i + 2] = v.z; tile[lr][lc + i + 3] = v.w;
  }
  __syncthreads();
  unsigned pk[8];
#pragma unroll
  for (int j = 0; j < 8; ++j) {
    u16 lo = f2bf(tile[lc + 2 * j][lr]);
    u16 hi = f2bf(tile[lc + 2 * j + 1][lr]);
    pk[j] = lo | ((unsigned)hi << 16);
  }
  u16* dst = WT + (size_t)(c0 + lr) * KD + k0 + lc;
  *(uint4*)(dst) = make_uint4(pk[0], pk[1], pk[2], pk[3]);
  *(uint4*)(dst + 8) = make_uint4(pk[4], pk[5], pk[6], pk[7]);
}

__global__ __launch_bounds__(256) void fused_prologue(const float* __restrict__ x,
                                                      const float* __restrict__ w_attn,
                                                      const float* __restrict__ w_proj,
                                                      u16* __restrict__ xb,
                                                      u16* __restrict__ wTa,
                                                      u16* __restrict__ wTp) {
  __shared__ float tile[64][65];
  const int b = blockIdx.x;
  const int t = threadIdx.x;
  if (b < 2048) {
    const int i = (b * 256 + t) * 8;
    float4 a = *(const float4*)(x + i);
    float4 c = *(const float4*)(x + i + 4);
    uint4 pk;
    pk.x = f2bf(a.x) | ((unsigned)f2bf(a.y) << 16);
    pk.y = f2bf(a.z) | ((unsigned)f2bf(a.w) << 16);
    pk.z = f2bf(c.x) | ((unsigned)f2bf(c.y) << 16);
    pk.w = f2bf(c.z) | ((unsigned)f2bf(c.w) << 16);
    *(uint4*)(xb + i) = pk;
  } else if (b < 2816) {
    const int id = b - 2048;
    transpose_tile(w_attn, wTa, 3072, 1024, (id % 48) * 64, (id / 48) * 64, tile, t);
  } else {
    const int id = b - 2816;
    transpose_tile(w_proj, wTp, 1024, 1024, (id % 16) * 64, (id / 16) * 64, tile, t);
  }
}

// -------- GEMM: C[M,N] = A[M,1024] * Bt[N,1024]^T + bias, BK=128 --------
// Tile 128 x BN=64 for BOTH gemms: 48KB LDS -> 3 blocks/CU (12 waves/CU).
// QKV grid 32x48 = 1536 blocks = 2 exact rounds; proj 32x16 = 512 blocks.
// (R15 lesson: bigger tiles cost VGPR slack and lose; R16's proj showed
// the small-tile/high-occupancy shape wins at K=1024.)
// XOR-swizzled As/Bs (pre-swizzled global_load_lds source + swizzled b128
// reads), conflict-free.
// MODE 0: scatter to q/k (bf16 [bh][t][64]) and V TRANSPOSED ([bh][d][t],
// packed b64 stores); MODE 1: fp32 out [M][NSIZE]
template<int NSIZE, int MODE, int BN>
__global__ __launch_bounds__(256) void gemm_bt(const u16* __restrict__ A,
                                               const u16* __restrict__ Bt,
                                               const float* __restrict__ bias,
                                               u16* __restrict__ qb,
                                               u16* __restrict__ kb,
                                               u16* __restrict__ vb,
                                               float* __restrict__ outp) {
  constexpr int K = 1024;
  constexpr int NT = BN / 32;          // n-fragments per wave
  __shared__ u16 As[128 * 128];
  __shared__ u16 Bs[BN * 128];
  const int tid = threadIdx.x;
  const int lane = tid & 63;
  const int wid = tid >> 6;
  const int l15 = lane & 15;
  const int g4 = lane >> 4;
  const int wm = (wid >> 1) * 64;
  const int wn = (wid & 1) * (BN / 2);
  const int row0 = blockIdx.x * 128;
  const int col0 = blockIdx.y * BN;

  f32x4 acc[4][NT] = {};

  for (int kt = 0; kt < K / 128; ++kt) {
    // stage A (2048 chunks) and B (BN*8 chunks); source pre-swizzled
#pragma unroll
    for (int cc = 0; cc < 8; ++cc) {
      const int c = tid + cc * 256;
      const int row = c >> 4;
      const int ch = (c & 15) ^ (row & 15);
      gload_lds16(A + (size_t)(row0 + row) * K + kt * 128 + ch * 8, As + c * 8);
    }
#pragma unroll
    for (int cc = 0; cc < BN / 16; ++cc) {
      const int c = tid + cc * 256;
      const int row = c >> 4;
      const int ch = (c & 15) ^ (row & 15);
      gload_lds16(Bt + (size_t)(col0 + row) * K + kt * 128 + ch * 8, Bs + c * 8);
    }
    asm volatile("s_waitcnt vmcnt(0)" ::: "memory");
    __builtin_amdgcn_s_barrier();
    asm volatile("" ::: "memory");

#pragma unroll
    for (int ks = 0; ks < 4; ++ks) {
      short8 af[4], bf[NT];
      const int chB = (((ks * 4 + g4) ^ l15) & 15) << 4;
#pragma unroll
      for (int mt = 0; mt < 4; ++mt) {
        const int row = wm + mt * 16 + l15;
        af[mt] = *(const short8*)((const char*)As + row * 256 + chB);
      }
#pragma unroll
      for (int nt = 0; nt < NT; ++nt) {
        const int row = wn + nt * 16 + l15;
        bf[nt] = *(const short8*)((const char*)Bs + row * 256 + chB);
      }
#pragma unroll
      for (int mt = 0; mt < 4; ++mt)
#pragma unroll
        for (int nt = 0; nt < NT; ++nt)
          acc[mt][nt] = __builtin_amdgcn_mfma_f32_16x16x32_bf16(af[mt], bf[nt], acc[mt][nt], 0, 0, 0);
    }

    asm volatile("" ::: "memory");
    __builtin_amdgcn_s_barrier();
  }

#pragma unroll
  for (int nt = 0; nt < NT; ++nt) {
    const int col = col0 + wn + nt * 16 + l15;
    const float bv = bias[col];
    if (MODE == 0) {
      const int part = col >> 10;
      const int h = (col >> 6) & 15;
      const int d = col & 63;
      u16* dp = part == 0 ? qb : kb;
#pragma unroll
      for (int mt = 0; mt < 4; ++mt) {
        if (part == 2) {
          const int t0 = row0 + wm + mt * 16 + g4 * 4;
          const int bidx = t0 >> 11;
          const int tt = t0 & 2047;
          const unsigned lo = f2bf(acc[mt][nt][0] + bv) | ((unsigned)f2bf(acc[mt][nt][1] + bv) << 16);
          const unsigned hi = f2bf(acc[mt][nt][2] + bv) | ((unsigned)f2bf(acc[mt][nt][3] + bv) << 16);
          *(uint2*)&vb[((size_t)((bidx << 4) + h) * 64 + d) * 2048 + tt] = make_uint2(lo, hi);
        } else {
#pragma unroll
          for (int r = 0; r < 4; ++r) {
            const int row = row0 + wm + mt * 16 + g4 * 4 + r;
            const int bidx = row >> 11;
            const int tt = row & 2047;
            dp[((size_t)((bidx << 4) + h) * 2048 + tt) * 64 + d] = f2bf(acc[mt][nt][r] + bv);
          }
        }
      }
    } else {
#pragma unroll
      for (int mt = 0; mt < 4; ++mt) {
#pragma unroll
        for (int r = 0; r < 4; ++r) {
          const int row = row0 + wm + mt * 16 + g4 * 4 + r;
          outp[(size_t)row * NSIZE + col] = acc[mt][nt][r] + bv;
        }
      }
    }
  }
}

// -------- flash attention: paired q-tiles + split-kv, VALU diet --------
// grid (32 bh, 24 y). LDS 40KB, launch_bounds (256,3) (NOT 4: R13 showed
// min-waves=4 clamps VGPR to 64 -> 58MB spill traffic, 1.7x slower).
__global__ __launch_bounds__(256, 3) void attn_fwd(const u16* __restrict__ Qb,
                                                   const u16* __restrict__ Kb,
                                                   const u16* __restrict__ Vtb,
                                                   u16* __restrict__ Yb,
                                                   char* __restrict__ pb) {
  __shared__ u16 Ks[2][64 * 64];
  __shared__ u16 Vs[2][64 * 64];
  __shared__ u16 Ps[4][1024];     // 2KB per wave, reused by both groups
  const int bh = blockIdx.x;
  const int y = blockIdx.y;
  int j, c0t, c1t, chunk, split;
  if (y < 8)       { j = 8 + y;  c0t = 0;  c1t = 15;        chunk = 0; split = 1; }
  else if (y < 16) { j = 15 - y; c0t = 0;  c1t = 2 * j + 1; chunk = 0; split = 0; }
  else             { j = y - 8;  c0t = 16; c1t = 2 * j + 1; chunk = 1; split = 1; }
  const int q0 = j * 128;
  const int tid = threadIdx.x;
  const int lane = tid & 63;
  const int wid = tid >> 6;
  const int l15 = lane & 15;
  const int g4 = lane >> 4;
  const size_t bhq = (size_t)bh * 2048 * 64;
  const u16* Kbase = Kb + bhq;
  const u16* Vbase = Vtb + bhq;  // [64 d][2048 t] per bh
  const float C2 = 0.18033688011112042f;  // 0.125 * log2(e)
  u16* Pw = &Ps[wid][0];
  const int wrow0 = q0 + wid * 32;       // wave's 32 q-rows

  short8 ones;
#pragma unroll
  for (int i = 0; i < 8; ++i) ones[i] = (short)0x3F80;  // bf16 1.0

  short8 qf[2][2];
#pragma unroll
  for (int g = 0; g < 2; ++g) {
    const u16* qp = Qb + bhq + (size_t)(wrow0 + g * 16 + l15) * 64 + g4 * 8;
    qf[g][0] = *(const short8*)(qp);
    qf[g][1] = *(const short8*)(qp + 32);
  }
  f32x4 accy[2][4] = {};
  float m_q[2] = {-1e30f, -1e30f};
  float m_r[2][4] = {{-1e30f, -1e30f, -1e30f, -1e30f}, {-1e30f, -1e30f, -1e30f, -1e30f}};
  float l_r[2][4] = {};

  int cur = 0;
#pragma unroll
  for (int cc = 0; cc < 2; ++cc) {
    const int c = tid + cc * 256;
    const int srow = c >> 3;
    const int sblk = (c & 7) ^ (srow & 7);
    gload_lds16(Kbase + (size_t)(c0t * 64 + srow) * 64 + sblk * 8, Ks[0] + c * 8);
    gload_lds16(Vbase + (size_t)srow * 2048 + c0t * 64 + sblk * 8, Vs[0] + c * 8);
  }

  for (int kv = c0t; kv <= c1t; ++kv) {
    const int kv0 = kv * 64;
    if (kv < c1t) {
      const int nx0 = kv0 + 64;
#pragma unroll
      for (int cc = 0; cc < 2; ++cc) {
        const int c = tid + cc * 256;
        const int srow = c >> 3;
        const int sblk = (c & 7) ^ (srow & 7);
        gload_lds16(Kbase + (size_t)(nx0 + srow) * 64 + sblk * 8, Ks[cur ^ 1] + c * 8);
        gload_lds16(Vbase + (size_t)srow * 2048 + nx0 + sblk * 8, Vs[cur ^ 1] + c * 8);
      }
      asm volatile("s_waitcnt vmcnt(4)" ::: "memory");
    } else {
      asm volatile("s_waitcnt vmcnt(0)" ::: "memory");
    }
    __builtin_amdgcn_s_barrier();
    asm volatile("" ::: "memory");

    if (kv0 <= wrow0 + 31) {   // wave-uniform skip of fully-masked tiles
      const u16* Kt = Ks[cur];
      const u16* Vt = Vs[cur];

      // ---- S^T = K Q^T, both groups, shared K fragments ----
      f32x4 s[2][4];
#pragma unroll
      for (int nt = 0; nt < 4; ++nt) {
        const int R = nt * 16 + l15;
        const int sw = (R & 7) << 4;
        short8 kf0 = *(const short8*)((const char*)Kt + R * 128 + ((g4 * 16) ^ sw));
        short8 kf1 = *(const short8*)((const char*)Kt + R * 128 + ((64 + g4 * 16) ^ sw));
        f32x4 z0 = __builtin_amdgcn_mfma_f32_16x16x32_bf16(kf0, qf[0][0], f32x4{}, 0, 0, 0);
        s[0][nt] = __builtin_amdgcn_mfma_f32_16x16x32_bf16(kf1, qf[0][1], z0, 0, 0, 0);
        f32x4 z1 = __builtin_amdgcn_mfma_f32_16x16x32_bf16(kf0, qf[1][0], f32x4{}, 0, 0, 0);
        s[1][nt] = __builtin_amdgcn_mfma_f32_16x16x32_bf16(kf1, qf[1][1], z1, 0, 0, 0);
      }

      // ---- per-group: mask, max (max3 chains), defer-max, exp, P round-trip --
      short8 pf[2][2];
#pragma unroll
      for (int g = 0; g < 2; ++g) {
        const int grow0 = wrow0 + g * 16;
        if (kv0 + 63 > grow0) {
          const int qg = grow0 + l15;
#pragma unroll
          for (int nt = 0; nt < 4; ++nt) {
            const int kbase = kv0 + nt * 16 + g4 * 4;
#pragma unroll
            for (int r = 0; r < 4; ++r)
              if (kbase + r > qg) s[g][nt][r] = -1e30f;
          }
        }
        // max3-friendly reduction chain over 16 values
        float mx = fmaxf(s[g][0][0], s[g][0][1]);
        mx = fmaxf(fmaxf(mx, s[g][0][2]), s[g][0][3]);
        mx = fmaxf(fmaxf(mx, s[g][1][0]), s[g][1][1]);
        mx = fmaxf(fmaxf(mx, s[g][1][2]), s[g][1][3]);
        mx = fmaxf(fmaxf(mx, s[g][2][0]), s[g][2][1]);
        mx = fmaxf(fmaxf(mx, s[g][2][2]), s[g][2][3]);
        mx = fmaxf(fmaxf(mx, s[g][3][0]), s[g][3][1]);
        mx = fmaxf(fmaxf(mx, s[g][3][2]), s[g][3][3]);
        mx = fmaxf(mx, __shfl_xor(mx, 16));
        mx = fmaxf(mx, __shfl_xor(mx, 32));
        if (!__all(mx <= m_q[g] + 44.0f)) {   // rescale path (rare, T13)
          m_q[g] = fmaxf(m_q[g], mx);
#pragma unroll
          for (int rr = 0; rr < 4; ++rr) {
            const float mn = __shfl(m_q[g], g4 * 4 + rr);
            const float al = __builtin_amdgcn_exp2f((m_r[g][rr] - mn) * C2);
            m_r[g][rr] = mn;
            l_r[g][rr] *= al;
#pragma unroll
            for (int nt = 0; nt < 4; ++nt) accy[g][nt][rr] *= al;
          }
        }
        const float m2 = m_q[g] * C2;
#pragma unroll
        for (int nt = 0; nt < 4; ++nt)
#pragma unroll
          for (int r = 0; r < 4; ++r)
            s[g][nt][r] = __builtin_amdgcn_exp2f(fmaf(s[g][nt][r], C2, -m2));

        // P -> per-wave LDS (HW cvt_pk packing, b64 swizzled), then read frags
#pragma unroll
        for (int nt = 0; nt < 4; ++nt) {
          const unsigned lo = cvt_pk_bf16(s[g][nt][0], s[g][nt][1]);
          const unsigned hi = cvt_pk_bf16(s[g][nt][2], s[g][nt][3]);
          const int colB = nt * 32 + g4 * 8;
          *(uint2*)((char*)Pw + l15 * 128 + (colB ^ ((l15 & 7) << 4))) = make_uint2(lo, hi);
        }
        {
          const int sw = (l15 & 7) << 4;
          pf[g][0] = *(const short8*)((const char*)Pw + l15 * 128 + ((g4 * 16) ^ sw));
          pf[g][1] = *(const short8*)((const char*)Pw + l15 * 128 + ((64 + g4 * 16) ^ sw));
        }
      }

      // ---- psum via ones-MFMA, PV with shared V fragments ----
#pragma unroll
      for (int g = 0; g < 2; ++g) {
        f32x4 ps = __builtin_amdgcn_mfma_f32_16x16x32_bf16(pf[g][0], ones, f32x4{}, 0, 0, 0);
        ps = __builtin_amdgcn_mfma_f32_16x16x32_bf16(pf[g][1], ones, ps, 0, 0, 0);
#pragma unroll
        for (int rr = 0; rr < 4; ++rr) l_r[g][rr] += ps[rr];
      }
#pragma unroll
      for (int nt = 0; nt < 4; ++nt) {
        const int R = nt * 16 + l15;
        const int sw = (R & 7) << 4;
        short8 vf0 = *(const short8*)((const char*)Vt + R * 128 + ((g4 * 16) ^ sw));
        short8 vf1 = *(const short8*)((const char*)Vt + R * 128 + ((64 + g4 * 16) ^ sw));
#pragma unroll
        for (int g = 0; g < 2; ++g) {
          accy[g][nt] = __builtin_amdgcn_mfma_f32_16x16x32_bf16(pf[g][0], vf0, accy[g][nt], 0, 0, 0);
          accy[g][nt] = __builtin_amdgcn_mfma_f32_16x16x32_bf16(pf[g][1], vf1, accy[g][nt], 0, 0, 0);
        }
      }
    }

    asm volatile("" ::: "memory");
    __builtin_amdgcn_s_barrier();
    cur ^= 1;
  }

  if (!split) {
#pragma unroll
    for (int g = 0; g < 2; ++g)
#pragma unroll
      for (int r = 0; r < 4; ++r) {
        const int row = wrow0 + g * 16 + g4 * 4 + r;
        const float inv = 1.0f / l_r[g][r];
        const size_t base = ((size_t)(bh >> 4) * 2048 + row) * 1024 + (bh & 15) * 64;
#pragma unroll
        for (int nt = 0; nt < 4; ++nt)
          Yb[base + nt * 16 + l15] = f2bf(accy[g][nt][r] * inv);
      }
  } else {
    char* slot = pb + ((size_t)(bh * 8 + (j - 8)) * 2 + chunk) * 17408;
    u16* O = (u16*)slot;
    float* mf = (float*)(slot + 16384);
    float* lf = (float*)(slot + 16896);
#pragma unroll
    for (int g = 0; g < 2; ++g)
#pragma unroll
      for (int r = 0; r < 4; ++r) {
        const int row = wid * 32 + g * 16 + g4 * 4 + r;   // local 0..127
        const float inv = 1.0f / l_r[g][r];
#pragma unroll
        for (int nt = 0; nt < 4; ++nt)
          O[row * 64 + nt * 16 + l15] = f2bf(accy[g][nt][r] * inv);
        if (l15 == 0) { mf[row] = m_r[g][r]; lf[row] = l_r[g][r]; }
      }
  }
}

// -------- combine split-kv partials --------
__global__ __launch_bounds__(256) void attn_combine(const char* __restrict__ pb,
                                                    u16* __restrict__ Yb) {
  const int x = blockIdx.x;        // 0..15
  const int bh = blockIdx.y;
  const int j = 8 + (x >> 1);
  const int half = x & 1;
  const int T = 2 * j + half;
  const char* s0 = pb + ((size_t)(bh * 8 + (j - 8)) * 2) * 17408;
  const char* s1 = s0 + 17408;
  const int tid = threadIdx.x;
  const int r64 = tid >> 2;        // 0..63
  const int rowl = half * 64 + r64;
  const int dc = (tid & 3) * 16;   // 0,16,32,48
  const float C2 = 0.18033688011112042f;
  const float m0 = ((const float*)(s0 + 16384))[rowl];
  const float m1 = ((const float*)(s1 + 16384))[rowl];
  const float l0 = ((const float*)(s0 + 16896))[rowl];
  const float l1 = ((const float*)(s1 + 16896))[rowl];
  const float m = fmaxf(m0, m1);
  const float w0 = __builtin_amdgcn_exp2f((m0 - m) * C2) * l0;
  const float w1 = __builtin_amdgcn_exp2f((m1 - m) * C2) * l1;
  const float inv = 1.0f / (w0 + w1);
  const float a0 = w0 * inv, a1 = w1 * inv;
  const u16* O0 = (const u16*)s0 + rowl * 64 + dc;
  const u16* O1 = (const u16*)s1 + rowl * 64 + dc;
  const int qrow = T * 64 + r64;
  u16* yp = Yb + ((size_t)(bh >> 4) * 2048 + qrow) * 1024 + (bh & 15) * 64 + dc;
  union { uint4 v; u16 h[8]; } a[2], b[2], o[2];
  a[0].v = *(const uint4*)O0; a[1].v = *(const uint4*)(O0 + 8);
  b[0].v = *(const uint4*)O1; b[1].v = *(const uint4*)(O1 + 8);
#pragma unroll
  for (int jj = 0; jj < 2; ++jj)
#pragma unroll
    for (int i = 0; i < 8; ++i)
      o[jj].h[i] = f2bf(bf2f(a[jj].h[i]) * a0 + bf2f(b[jj].h[i]) * a1);
  *(uint4*)yp = o[0].v;
  *(uint4*)(yp + 8) = o[1].v;
}

extern "C" void kernel_launch(void* const* d_in, const int* in_sizes, int n_in,
                              void* d_out, int out_size, void* d_ws, size_t ws_size,
                              hipStream_t stream) {
  const float* x      = (const float*)d_in[0];
  const float* w_attn = (const float*)d_in[1];
  const float* b_attn = (const float*)d_in[2];
  const float* w_proj = (const float*)d_in[3];
  const float* b_proj = (const float*)d_in[4];
  float* out = (float*)d_out;
  char* ws = (char*)d_ws;

  u16* xb  = (u16*)(ws + (size_t)0);           // 8 MB: x bf16 [4096][1024]
  u16* wTa = (u16*)(ws + ((size_t)8  << 20));  // 6 MB: w_attn^T bf16 [3072][1024]
  u16* wTp = (u16*)(ws + ((size_t)14 << 20));  // 2 MB: w_proj^T bf16 [1024][1024]
  u16* qb  = (u16*)(ws + ((size_t)16 << 20));  // 8 MB: Q [32][2048][64]
  u16* kb  = (u16*)(ws + ((size_t)24 << 20));  // 8 MB: K [32][2048][64]
  u16* vb  = (u16*)(ws + ((size_t)32 << 20));  // 8 MB: V^T [32][64][2048]
  u16* yb  = (u16*)(ws + ((size_t)40 << 20));  // 8 MB: y bf16 [4096][1024]
  char* pb = ws;   // split-kv partials overlay xb+wTa (dead after QKV GEMM)

  fused_prologue<<<3072, 256, 0, stream>>>(x, w_attn, w_proj, xb, wTa, wTp);
  gemm_bt<3072, 0, 64><<<dim3(32, 48), 256, 0, stream>>>(xb, wTa, b_attn, qb, kb, vb, nullptr);
  attn_fwd<<<dim3(32, 24), 256, 0, stream>>>(qb, kb, vb, yb, pb);
  attn_combine<<<dim3(16, 32), 256, 0, stream>>>(pb, yb);
  gemm_bt<1024, 1, 64><<<dim3(32, 16), 256, 0, stream>>>(yb, wTp, b_proj, nullptr, nullptr, nullptr, out);
}

// Round 18
// 102.341 us; speedup vs baseline: 1.0391x; 1.0391x over previous
//
#include <hip/hip_runtime.h>
#include <hip/hip_bf16.h>
#include <math.h>

typedef __attribute__((ext_vector_type(8))) short short8;
typedef __attribute__((ext_vector_type(4))) float f32x4;
typedef unsigned short u16;

static __device__ __forceinline__ u16 f2bf(float f) {
  union { float f; unsigned u; } v; v.f = f;
  unsigned r = v.u + 0x7fffu + ((v.u >> 16) & 1u);
  return (u16)(r >> 16);
}

static __device__ __forceinline__ float bf2f(u16 h) {
  union { unsigned u; float f; } v; v.u = ((unsigned)h) << 16;
  return v.f;
}

// gfx950 HW packed f32->bf16 convert (no builtin; inline asm per T12)
static __device__ __forceinline__ unsigned cvt_pk_bf16(float lo, float hi) {
  unsigned r;
  asm("v_cvt_pk_bf16_f32 %0, %1, %2" : "=v"(r) : "v"(lo), "v"(hi));
  return r;
}

static __device__ __forceinline__ void gload_lds16(const void* g, void* l) {
  __builtin_amdgcn_global_load_lds(
      (const __attribute__((address_space(1))) void*)g,
      (__attribute__((address_space(3))) void*)l, 16, 0, 0);
}

// -------- fused prologue: cvt x -> bf16 | transpose w_attn | transpose w_proj --
__device__ __forceinline__ void transpose_tile(const float* __restrict__ W,
                                               u16* __restrict__ WT,
                                               int ND, int KD, int c0, int k0,
                                               float (*tile)[65], int t) {
  const int lr = t >> 2;
  const int lc = (t & 3) * 16;
  const float* src = W + (size_t)(k0 + lr) * ND + c0 + lc;
#pragma unroll
  for (int i = 0; i < 16; i += 4) {
    float4 v = *(const float4*)(src + i);
    tile[lr][lc + i] = v.x; tile[lr][lc + i + 1] = v.y;
    tile[lr][lc + i + 2] = v.z; tile[lr][lc + i + 3] = v.w;
  }
  __syncthreads();
  unsigned pk[8];
#pragma unroll
  for (int j = 0; j < 8; ++j) {
    u16 lo = f2bf(tile[lc + 2 * j][lr]);
    u16 hi = f2bf(tile[lc + 2 * j + 1][lr]);
    pk[j] = lo | ((unsigned)hi << 16);
  }
  u16* dst = WT + (size_t)(c0 + lr) * KD + k0 + lc;
  *(uint4*)(dst) = make_uint4(pk[0], pk[1], pk[2], pk[3]);
  *(uint4*)(dst + 8) = make_uint4(pk[4], pk[5], pk[6], pk[7]);
}

__global__ __launch_bounds__(256) void fused_prologue(const float* __restrict__ x,
                                                      const float* __restrict__ w_attn,
                                                      const float* __restrict__ w_proj,
                                                      u16* __restrict__ xb,
                                                      u16* __restrict__ wTa,
                                                      u16* __restrict__ wTp) {
  __shared__ float tile[64][65];
  const int b = blockIdx.x;
  const int t = threadIdx.x;
  if (b < 2048) {
    const int i = (b * 256 + t) * 8;
    float4 a = *(const float4*)(x + i);
    float4 c = *(const float4*)(x + i + 4);
    uint4 pk;
    pk.x = f2bf(a.x) | ((unsigned)f2bf(a.y) << 16);
    pk.y = f2bf(a.z) | ((unsigned)f2bf(a.w) << 16);
    pk.z = f2bf(c.x) | ((unsigned)f2bf(c.y) << 16);
    pk.w = f2bf(c.z) | ((unsigned)f2bf(c.w) << 16);
    *(uint4*)(xb + i) = pk;
  } else if (b < 2816) {
    const int id = b - 2048;
    transpose_tile(w_attn, wTa, 3072, 1024, (id % 48) * 64, (id / 48) * 64, tile, t);
  } else {
    const int id = b - 2816;
    transpose_tile(w_proj, wTp, 1024, 1024, (id % 16) * 64, (id / 16) * 64, tile, t);
  }
}

// -------- GEMM: C[M,N] = A[M,1024] * Bt[N,1024]^T + bias --------
// Tile 128x64, BK=64, DOUBLE-BUFFERED with counted vmcnt (T4): per iter,
// stage(kt+1) is issued BEFORE the barrier and vmcnt(6) waits only on the
// PREVIOUS iteration's 6 loads (which had a full compute phase to land) --
// removes the per-iter full drain that paced R16/R17 (~41us, MfmaUtil 23%).
// LDS 48KB -> 3 blocks/CU. XOR swizzle (c&7)^(row&7) both-sides.
// MODE 0: scatter q/k ([bh][t][64]) + V^T ([bh][d][t]); MODE 1: fp32 out.
template<int NSIZE, int MODE, int BN>
__global__ __launch_bounds__(256) void gemm_bt(const u16* __restrict__ A,
                                               const u16* __restrict__ Bt,
                                               const float* __restrict__ bias,
                                               u16* __restrict__ qb,
                                               u16* __restrict__ kb,
                                               u16* __restrict__ vb,
                                               float* __restrict__ outp) {
  constexpr int K = 1024;
  constexpr int NT = BN / 32;          // 2
  static_assert(BN == 64, "vmcnt literal assumes BN=64");
  __shared__ u16 As[2][128 * 64];
  __shared__ u16 Bs[2][64 * 64];
  const int tid = threadIdx.x;
  const int lane = tid & 63;
  const int wid = tid >> 6;
  const int l15 = lane & 15;
  const int g4 = lane >> 4;
  const int wm = (wid >> 1) * 64;
  const int wn = (wid & 1) * 32;
  const int row0 = blockIdx.x * 128;
  const int col0 = blockIdx.y * BN;

  f32x4 acc[4][NT] = {};

  // A: 1024 chunks (4/thread), B: 512 chunks (2/thread); src pre-swizzled
  // prologue: stage kt=0 into buf 0
#pragma unroll
  for (int i = 0; i < 4; ++i) {
    const int c = tid + i * 256;
    const int row = c >> 3;
    const int blk = (c & 7) ^ (row & 7);
    gload_lds16(A + (size_t)(row0 + row) * K + blk * 8, As[0] + c * 8);
  }
#pragma unroll
  for (int i = 0; i < 2; ++i) {
    const int c = tid + i * 256;
    const int row = c >> 3;
    const int blk = (c & 7) ^ (row & 7);
    gload_lds16(Bt + (size_t)(col0 + row) * K + blk * 8, Bs[0] + c * 8);
  }

  int cur = 0;
  for (int kt = 0; kt < K / 64; ++kt) {
    if (kt + 1 < K / 64) {
      const int ko = (kt + 1) * 64;
#pragma unroll
      for (int i = 0; i < 4; ++i) {
        const int c = tid + i * 256;
        const int row = c >> 3;
        const int blk = (c & 7) ^ (row & 7);
        gload_lds16(A + (size_t)(row0 + row) * K + ko + blk * 8, As[cur ^ 1] + c * 8);
      }
#pragma unroll
      for (int i = 0; i < 2; ++i) {
        const int c = tid + i * 256;
        const int row = c >> 3;
        const int blk = (c & 7) ^ (row & 7);
        gload_lds16(Bt + (size_t)(col0 + row) * K + ko + blk * 8, Bs[cur ^ 1] + c * 8);
      }
      asm volatile("s_waitcnt vmcnt(6)" ::: "memory");
    } else {
      asm volatile("s_waitcnt vmcnt(0)" ::: "memory");
    }
    __builtin_amdgcn_s_barrier();
    asm volatile("" ::: "memory");

    const u16* Ac = As[cur];
    const u16* Bc = Bs[cur];
#pragma unroll
    for (int ks = 0; ks < 2; ++ks) {
      short8 af[4], bf[NT];
      const int B = ks * 64 + g4 * 16;
      const int sw = (l15 & 7) << 4;
#pragma unroll
      for (int mt = 0; mt < 4; ++mt)
        af[mt] = *(const short8*)((const char*)Ac + (wm + mt * 16 + l15) * 128 + (B ^ sw));
#pragma unroll
      for (int nt = 0; nt < NT; ++nt)
        bf[nt] = *(const short8*)((const char*)Bc + (wn + nt * 16 + l15) * 128 + (B ^ sw));
#pragma unroll
      for (int mt = 0; mt < 4; ++mt)
#pragma unroll
        for (int nt = 0; nt < NT; ++nt)
          acc[mt][nt] = __builtin_amdgcn_mfma_f32_16x16x32_bf16(af[mt], bf[nt], acc[mt][nt], 0, 0, 0);
    }

    asm volatile("" ::: "memory");
    __builtin_amdgcn_s_barrier();
    cur ^= 1;
  }

#pragma unroll
  for (int nt = 0; nt < NT; ++nt) {
    const int col = col0 + wn + nt * 16 + l15;
    const float bv = bias[col];
    if (MODE == 0) {
      const int part = col >> 10;
      const int h = (col >> 6) & 15;
      const int d = col & 63;
      u16* dp = part == 0 ? qb : kb;
#pragma unroll
      for (int mt = 0; mt < 4; ++mt) {
        if (part == 2) {
          const int t0 = row0 + wm + mt * 16 + g4 * 4;
          const int bidx = t0 >> 11;
          const int tt = t0 & 2047;
          const unsigned lo = f2bf(acc[mt][nt][0] + bv) | ((unsigned)f2bf(acc[mt][nt][1] + bv) << 16);
          const unsigned hi = f2bf(acc[mt][nt][2] + bv) | ((unsigned)f2bf(acc[mt][nt][3] + bv) << 16);
          *(uint2*)&vb[((size_t)((bidx << 4) + h) * 64 + d) * 2048 + tt] = make_uint2(lo, hi);
        } else {
#pragma unroll
          for (int r = 0; r < 4; ++r) {
            const int row = row0 + wm + mt * 16 + g4 * 4 + r;
            const int bidx = row >> 11;
            const int tt = row & 2047;
            dp[((size_t)((bidx << 4) + h) * 2048 + tt) * 64 + d] = f2bf(acc[mt][nt][r] + bv);
          }
        }
      }
    } else {
#pragma unroll
      for (int mt = 0; mt < 4; ++mt) {
#pragma unroll
        for (int r = 0; r < 4; ++r) {
          const int row = row0 + wm + mt * 16 + g4 * 4 + r;
          outp[(size_t)row * NSIZE + col] = acc[mt][nt][r] + bv;
        }
      }
    }
  }
}

// -------- flash attention: paired q-tiles + split-kv, VALU diet --------
// grid (32 bh, 24 y). LDS 40KB, launch_bounds (256,3) (NOT 4: R13 showed
// min-waves=4 clamps VGPR to 64 -> 58MB spill traffic, 1.7x slower).
__global__ __launch_bounds__(256, 3) void attn_fwd(const u16* __restrict__ Qb,
                                                   const u16* __restrict__ Kb,
                                                   const u16* __restrict__ Vtb,
                                                   u16* __restrict__ Yb,
                                                   char* __restrict__ pb) {
  __shared__ u16 Ks[2][64 * 64];
  __shared__ u16 Vs[2][64 * 64];
  __shared__ u16 Ps[4][1024];     // 2KB per wave, reused by both groups
  const int bh = blockIdx.x;
  const int y = blockIdx.y;
  int j, c0t, c1t, chunk, split;
  if (y < 8)       { j = 8 + y;  c0t = 0;  c1t = 15;        chunk = 0; split = 1; }
  else if (y < 16) { j = 15 - y; c0t = 0;  c1t = 2 * j + 1; chunk = 0; split = 0; }
  else             { j = y - 8;  c0t = 16; c1t = 2 * j + 1; chunk = 1; split = 1; }
  const int q0 = j * 128;
  const int tid = threadIdx.x;
  const int lane = tid & 63;
  const int wid = tid >> 6;
  const int l15 = lane & 15;
  const int g4 = lane >> 4;
  const size_t bhq = (size_t)bh * 2048 * 64;
  const u16* Kbase = Kb + bhq;
  const u16* Vbase = Vtb + bhq;  // [64 d][2048 t] per bh
  const float C2 = 0.18033688011112042f;  // 0.125 * log2(e)
  u16* Pw = &Ps[wid][0];
  const int wrow0 = q0 + wid * 32;       // wave's 32 q-rows

  short8 ones;
#pragma unroll
  for (int i = 0; i < 8; ++i) ones[i] = (short)0x3F80;  // bf16 1.0

  short8 qf[2][2];
#pragma unroll
  for (int g = 0; g < 2; ++g) {
    const u16* qp = Qb + bhq + (size_t)(wrow0 + g * 16 + l15) * 64 + g4 * 8;
    qf[g][0] = *(const short8*)(qp);
    qf[g][1] = *(const short8*)(qp + 32);
  }
  f32x4 accy[2][4] = {};
  float m_q[2] = {-1e30f, -1e30f};
  float m_r[2][4] = {{-1e30f, -1e30f, -1e30f, -1e30f}, {-1e30f, -1e30f, -1e30f, -1e30f}};
  float l_r[2][4] = {};

  int cur = 0;
#pragma unroll
  for (int cc = 0; cc < 2; ++cc) {
    const int c = tid + cc * 256;
    const int srow = c >> 3;
    const int sblk = (c & 7) ^ (srow & 7);
    gload_lds16(Kbase + (size_t)(c0t * 64 + srow) * 64 + sblk * 8, Ks[0] + c * 8);
    gload_lds16(Vbase + (size_t)srow * 2048 + c0t * 64 + sblk * 8, Vs[0] + c * 8);
  }

  for (int kv = c0t; kv <= c1t; ++kv) {
    const int kv0 = kv * 64;
    if (kv < c1t) {
      const int nx0 = kv0 + 64;
#pragma unroll
      for (int cc = 0; cc < 2; ++cc) {
        const int c = tid + cc * 256;
        const int srow = c >> 3;
        const int sblk = (c & 7) ^ (srow & 7);
        gload_lds16(Kbase + (size_t)(nx0 + srow) * 64 + sblk * 8, Ks[cur ^ 1] + c * 8);
        gload_lds16(Vbase + (size_t)srow * 2048 + nx0 + sblk * 8, Vs[cur ^ 1] + c * 8);
      }
      asm volatile("s_waitcnt vmcnt(4)" ::: "memory");
    } else {
      asm volatile("s_waitcnt vmcnt(0)" ::: "memory");
    }
    __builtin_amdgcn_s_barrier();
    asm volatile("" ::: "memory");

    if (kv0 <= wrow0 + 31) {   // wave-uniform skip of fully-masked tiles
      const u16* Kt = Ks[cur];
      const u16* Vt = Vs[cur];

      // ---- S^T = K Q^T, both groups, shared K fragments ----
      f32x4 s[2][4];
#pragma unroll
      for (int nt = 0; nt < 4; ++nt) {
        const int R = nt * 16 + l15;
        const int sw = (R & 7) << 4;
        short8 kf0 = *(const short8*)((const char*)Kt + R * 128 + ((g4 * 16) ^ sw));
        short8 kf1 = *(const short8*)((const char*)Kt + R * 128 + ((64 + g4 * 16) ^ sw));
        f32x4 z0 = __builtin_amdgcn_mfma_f32_16x16x32_bf16(kf0, qf[0][0], f32x4{}, 0, 0, 0);
        s[0][nt] = __builtin_amdgcn_mfma_f32_16x16x32_bf16(kf1, qf[0][1], z0, 0, 0, 0);
        f32x4 z1 = __builtin_amdgcn_mfma_f32_16x16x32_bf16(kf0, qf[1][0], f32x4{}, 0, 0, 0);
        s[1][nt] = __builtin_amdgcn_mfma_f32_16x16x32_bf16(kf1, qf[1][1], z1, 0, 0, 0);
      }

      // ---- per-group: mask, max (max3 chains), defer-max, exp, P round-trip --
      short8 pf[2][2];
#pragma unroll
      for (int g = 0; g < 2; ++g) {
        const int grow0 = wrow0 + g * 16;
        if (kv0 + 63 > grow0) {
          const int qg = grow0 + l15;
#pragma unroll
          for (int nt = 0; nt < 4; ++nt) {
            const int kbase = kv0 + nt * 16 + g4 * 4;
#pragma unroll
            for (int r = 0; r < 4; ++r)
              if (kbase + r > qg) s[g][nt][r] = -1e30f;
          }
        }
        // max3-friendly reduction chain over 16 values
        float mx = fmaxf(s[g][0][0], s[g][0][1]);
        mx = fmaxf(fmaxf(mx, s[g][0][2]), s[g][0][3]);
        mx = fmaxf(fmaxf(mx, s[g][1][0]), s[g][1][1]);
        mx = fmaxf(fmaxf(mx, s[g][1][2]), s[g][1][3]);
        mx = fmaxf(fmaxf(mx, s[g][2][0]), s[g][2][1]);
        mx = fmaxf(fmaxf(mx, s[g][2][2]), s[g][2][3]);
        mx = fmaxf(fmaxf(mx, s[g][3][0]), s[g][3][1]);
        mx = fmaxf(fmaxf(mx, s[g][3][2]), s[g][3][3]);
        mx = fmaxf(mx, __shfl_xor(mx, 16));
        mx = fmaxf(mx, __shfl_xor(mx, 32));
        if (!__all(mx <= m_q[g] + 44.0f)) {   // rescale path (rare, T13)
          m_q[g] = fmaxf(m_q[g], mx);
#pragma unroll
          for (int rr = 0; rr < 4; ++rr) {
            const float mn = __shfl(m_q[g], g4 * 4 + rr);
            const float al = __builtin_amdgcn_exp2f((m_r[g][rr] - mn) * C2);
            m_r[g][rr] = mn;
            l_r[g][rr] *= al;
#pragma unroll
            for (int nt = 0; nt < 4; ++nt) accy[g][nt][rr] *= al;
          }
        }
        const float m2 = m_q[g] * C2;
#pragma unroll
        for (int nt = 0; nt < 4; ++nt)
#pragma unroll
          for (int r = 0; r < 4; ++r)
            s[g][nt][r] = __builtin_amdgcn_exp2f(fmaf(s[g][nt][r], C2, -m2));

        // P -> per-wave LDS (HW cvt_pk packing, b64 swizzled), then read frags
#pragma unroll
        for (int nt = 0; nt < 4; ++nt) {
          const unsigned lo = cvt_pk_bf16(s[g][nt][0], s[g][nt][1]);
          const unsigned hi = cvt_pk_bf16(s[g][nt][2], s[g][nt][3]);
          const int colB = nt * 32 + g4 * 8;
          *(uint2*)((char*)Pw + l15 * 128 + (colB ^ ((l15 & 7) << 4))) = make_uint2(lo, hi);
        }
        {
          const int sw = (l15 & 7) << 4;
          pf[g][0] = *(const short8*)((const char*)Pw + l15 * 128 + ((g4 * 16) ^ sw));
          pf[g][1] = *(const short8*)((const char*)Pw + l15 * 128 + ((64 + g4 * 16) ^ sw));
        }
      }

      // ---- psum via ones-MFMA, PV with shared V fragments ----
#pragma unroll
      for (int g = 0; g < 2; ++g) {
        f32x4 ps = __builtin_amdgcn_mfma_f32_16x16x32_bf16(pf[g][0], ones, f32x4{}, 0, 0, 0);
        ps = __builtin_amdgcn_mfma_f32_16x16x32_bf16(pf[g][1], ones, ps, 0, 0, 0);
#pragma unroll
        for (int rr = 0; rr < 4; ++rr) l_r[g][rr] += ps[rr];
      }
#pragma unroll
      for (int nt = 0; nt < 4; ++nt) {
        const int R = nt * 16 + l15;
        const int sw = (R & 7) << 4;
        short8 vf0 = *(const short8*)((const char*)Vt + R * 128 + ((g4 * 16) ^ sw));
        short8 vf1 = *(const short8*)((const char*)Vt + R * 128 + ((64 + g4 * 16) ^ sw));
#pragma unroll
        for (int g = 0; g < 2; ++g) {
          accy[g][nt] = __builtin_amdgcn_mfma_f32_16x16x32_bf16(pf[g][0], vf0, accy[g][nt], 0, 0, 0);
          accy[g][nt] = __builtin_amdgcn_mfma_f32_16x16x32_bf16(pf[g][1], vf1, accy[g][nt], 0, 0, 0);
        }
      }
    }

    asm volatile("" ::: "memory");
    __builtin_amdgcn_s_barrier();
    cur ^= 1;
  }

  if (!split) {
#pragma unroll
    for (int g = 0; g < 2; ++g)
#pragma unroll
      for (int r = 0; r < 4; ++r) {
        const int row = wrow0 + g * 16 + g4 * 4 + r;
        const float inv = 1.0f / l_r[g][r];
        const size_t base = ((size_t)(bh >> 4) * 2048 + row) * 1024 + (bh & 15) * 64;
#pragma unroll
        for (int nt = 0; nt < 4; ++nt)
          Yb[base + nt * 16 + l15] = f2bf(accy[g][nt][r] * inv);
      }
  } else {
    char* slot = pb + ((size_t)(bh * 8 + (j - 8)) * 2 + chunk) * 17408;
    u16* O = (u16*)slot;
    float* mf = (float*)(slot + 16384);
    float* lf = (float*)(slot + 16896);
#pragma unroll
    for (int g = 0; g < 2; ++g)
#pragma unroll
      for (int r = 0; r < 4; ++r) {
        const int row = wid * 32 + g * 16 + g4 * 4 + r;   // local 0..127
        const float inv = 1.0f / l_r[g][r];
#pragma unroll
        for (int nt = 0; nt < 4; ++nt)
          O[row * 64 + nt * 16 + l15] = f2bf(accy[g][nt][r] * inv);
        if (l15 == 0) { mf[row] = m_r[g][r]; lf[row] = l_r[g][r]; }
      }
  }
}

// -------- combine split-kv partials --------
__global__ __launch_bounds__(256) void attn_combine(const char* __restrict__ pb,
                                                    u16* __restrict__ Yb) {
  const int x = blockIdx.x;        // 0..15
  const int bh = blockIdx.y;
  const int j = 8 + (x >> 1);
  const int half = x & 1;
  const int T = 2 * j + half;
  const char* s0 = pb + ((size_t)(bh * 8 + (j - 8)) * 2) * 17408;
  const char* s1 = s0 + 17408;
  const int tid = threadIdx.x;
  const int r64 = tid >> 2;        // 0..63
  const int rowl = half * 64 + r64;
  const int dc = (tid & 3) * 16;   // 0,16,32,48
  const float C2 = 0.18033688011112042f;
  const float m0 = ((const float*)(s0 + 16384))[rowl];
  const float m1 = ((const float*)(s1 + 16384))[rowl];
  const float l0 = ((const float*)(s0 + 16896))[rowl];
  const float l1 = ((const float*)(s1 + 16896))[rowl];
  const float m = fmaxf(m0, m1);
  const float w0 = __builtin_amdgcn_exp2f((m0 - m) * C2) * l0;
  const float w1 = __builtin_amdgcn_exp2f((m1 - m) * C2) * l1;
  const float inv = 1.0f / (w0 + w1);
  const float a0 = w0 * inv, a1 = w1 * inv;
  const u16* O0 = (const u16*)s0 + rowl * 64 + dc;
  const u16* O1 = (const u16*)s1 + rowl * 64 + dc;
  const int qrow = T * 64 + r64;
  u16* yp = Yb + ((size_t)(bh >> 4) * 2048 + qrow) * 1024 + (bh & 15) * 64 + dc;
  union { uint4 v; u16 h[8]; } a[2], b[2], o[2];
  a[0].v = *(const uint4*)O0; a[1].v = *(const uint4*)(O0 + 8);
  b[0].v = *(const uint4*)O1; b[1].v = *(const uint4*)(O1 + 8);
#pragma unroll
  for (int jj = 0; jj < 2; ++jj)
#pragma unroll
    for (int i = 0; i < 8; ++i)
      o[jj].h[i] = f2bf(bf2f(a[jj].h[i]) * a0 + bf2f(b[jj].h[i]) * a1);
  *(uint4*)yp = o[0].v;
  *(uint4*)(yp + 8) = o[1].v;
}

extern "C" void kernel_launch(void* const* d_in, const int* in_sizes, int n_in,
                              void* d_out, int out_size, void* d_ws, size_t ws_size,
                              hipStream_t stream) {
  const float* x      = (const float*)d_in[0];
  const float* w_attn = (const float*)d_in[1];
  const float* b_attn = (const float*)d_in[2];
  const float* w_proj = (const float*)d_in[3];
  const float* b_proj = (const float*)d_in[4];
  float* out = (float*)d_out;
  char* ws = (char*)d_ws;

  u16* xb  = (u16*)(ws + (size_t)0);           // 8 MB: x bf16 [4096][1024]
  u16* wTa = (u16*)(ws + ((size_t)8  << 20));  // 6 MB: w_attn^T bf16 [3072][1024]
  u16* wTp = (u16*)(ws + ((size_t)14 << 20));  // 2 MB: w_proj^T bf16 [1024][1024]
  u16* qb  = (u16*)(ws + ((size_t)16 << 20));  // 8 MB: Q [32][2048][64]
  u16* kb  = (u16*)(ws + ((size_t)24 << 20));  // 8 MB: K [32][2048][64]
  u16* vb  = (u16*)(ws + ((size_t)32 << 20));  // 8 MB: V^T [32][64][2048]
  u16* yb  = (u16*)(ws + ((size_t)40 << 20));  // 8 MB: y bf16 [4096][1024]
  char* pb = ws;   // split-kv partials overlay xb+wTa (dead after QKV GEMM)

  fused_prologue<<<3072, 256, 0, stream>>>(x, w_attn, w_proj, xb, wTa, wTp);
  gemm_bt<3072, 0, 64><<<dim3(32, 48), 256, 0, stream>>>(xb, wTa, b_attn, qb, kb, vb, nullptr);
  attn_fwd<<<dim3(32, 24), 256, 0, stream>>>(qb, kb, vb, yb, pb);
  attn_combine<<<dim3(16, 32), 256, 0, stream>>>(pb, yb);
  gemm_bt<1024, 1, 64><<<dim3(32, 16), 256, 0, stream>>>(yb, wTp, b_proj, nullptr, nullptr, nullptr, out);
}

// Round 20
// 102.273 us; speedup vs baseline: 1.0398x; 1.0007x over previous
//
#include <hip/hip_runtime.h>
#include <hip/hip_bf16.h>
#include <math.h>

typedef __attribute__((ext_vector_type(8))) short short8;
typedef __attribute__((ext_vector_type(4))) float f32x4;
typedef unsigned short u16;

static __device__ __forceinline__ u16 f2bf(float f) {
  union { float f; unsigned u; } v; v.f = f;
  unsigned r = v.u + 0x7fffu + ((v.u >> 16) & 1u);
  return (u16)(r >> 16);
}

static __device__ __forceinline__ float bf2f(u16 h) {
  union { unsigned u; float f; } v; v.u = ((unsigned)h) << 16;
  return v.f;
}

// gfx950 HW packed f32->bf16 convert (no builtin; inline asm per T12)
static __device__ __forceinline__ unsigned cvt_pk_bf16(float lo, float hi) {
  unsigned r;
  asm("v_cvt_pk_bf16_f32 %0, %1, %2" : "=v"(r) : "v"(lo), "v"(hi));
  return r;
}

static __device__ __forceinline__ void gload_lds16(const void* g, void* l) {
  __builtin_amdgcn_global_load_lds(
      (const __attribute__((address_space(1))) void*)g,
      (__attribute__((address_space(3))) void*)l, 16, 0, 0);
}

// -------- fused prologue: cvt x -> bf16 | transpose w_attn | transpose w_proj --
__device__ __forceinline__ void transpose_tile(const float* __restrict__ W,
                                               u16* __restrict__ WT,
                                               int ND, int KD, int c0, int k0,
                                               float (*tile)[65], int t) {
  const int lr = t >> 2;
  const int lc = (t & 3) * 16;
  const float* src = W + (size_t)(k0 + lr) * ND + c0 + lc;
#pragma unroll
  for (int i = 0; i < 16; i += 4) {
    float4 v = *(const float4*)(src + i);
    tile[lr][lc + i] = v.x; tile[lr][lc + i + 1] = v.y;
    tile[lr][lc + i + 2] = v.z; tile[lr][lc + i + 3] = v.w;
  }
  __syncthreads();
  unsigned pk[8];
#pragma unroll
  for (int j = 0; j < 8; ++j) {
    u16 lo = f2bf(tile[lc + 2 * j][lr]);
    u16 hi = f2bf(tile[lc + 2 * j + 1][lr]);
    pk[j] = lo | ((unsigned)hi << 16);
  }
  u16* dst = WT + (size_t)(c0 + lr) * KD + k0 + lc;
  *(uint4*)(dst) = make_uint4(pk[0], pk[1], pk[2], pk[3]);
  *(uint4*)(dst + 8) = make_uint4(pk[4], pk[5], pk[6], pk[7]);
}

__global__ __launch_bounds__(256) void fused_prologue(const float* __restrict__ x,
                                                      const float* __restrict__ w_attn,
                                                      const float* __restrict__ w_proj,
                                                      u16* __restrict__ xb,
                                                      u16* __restrict__ wTa,
                                                      u16* __restrict__ wTp) {
  __shared__ float tile[64][65];
  const int b = blockIdx.x;
  const int t = threadIdx.x;
  if (b < 2048) {
    const int i = (b * 256 + t) * 8;
    float4 a = *(const float4*)(x + i);
    float4 c = *(const float4*)(x + i + 4);
    uint4 pk;
    pk.x = f2bf(a.x) | ((unsigned)f2bf(a.y) << 16);
    pk.y = f2bf(a.z) | ((unsigned)f2bf(a.w) << 16);
    pk.z = f2bf(c.x) | ((unsigned)f2bf(c.y) << 16);
    pk.w = f2bf(c.z) | ((unsigned)f2bf(c.w) << 16);
    *(uint4*)(xb + i) = pk;
  } else if (b < 2816) {
    const int id = b - 2048;
    transpose_tile(w_attn, wTa, 3072, 1024, (id % 48) * 64, (id / 48) * 64, tile, t);
  } else {
    const int id = b - 2816;
    transpose_tile(w_proj, wTp, 1024, 1024, (id % 16) * 64, (id / 16) * 64, tile, t);
  }
}

// -------- GEMM: C[M,N] = A[M,1024] * Bt[N,1024]^T + bias --------
// Tile 128x64, BK=64, DOUBLE-BUFFERED with counted vmcnt (T4): stage(kt+1)
// issued BEFORE the barrier; vmcnt(6) waits only on the PREVIOUS iteration's
// loads (a full compute phase to land). LDS 48KB -> 3 blocks/CU.
// XOR swizzle (c&7)^(row&7) both-sides (conflict-free, R10-verified).
// MODE 0: scatter q/k ([bh][t][64]) + V^T ([bh][d][t]); MODE 1: fp32 out.
template<int NSIZE, int MODE, int BN>
__global__ __launch_bounds__(256) void gemm_bt(const u16* __restrict__ A,
                                               const u16* __restrict__ Bt,
                                               const float* __restrict__ bias,
                                               u16* __restrict__ qb,
                                               u16* __restrict__ kb,
                                               u16* __restrict__ vb,
                                               float* __restrict__ outp) {
  constexpr int K = 1024;
  constexpr int NT = BN / 32;          // 2
  static_assert(BN == 64, "vmcnt literal assumes BN=64");
  __shared__ u16 As[2][128 * 64];
  __shared__ u16 Bs[2][64 * 64];
  const int tid = threadIdx.x;
  const int lane = tid & 63;
  const int wid = tid >> 6;
  const int l15 = lane & 15;
  const int g4 = lane >> 4;
  const int wm = (wid >> 1) * 64;
  const int wn = (wid & 1) * 32;
  const int row0 = blockIdx.x * 128;
  const int col0 = blockIdx.y * BN;

  f32x4 acc[4][NT] = {};

#pragma unroll
  for (int i = 0; i < 4; ++i) {
    const int c = tid + i * 256;
    const int row = c >> 3;
    const int blk = (c & 7) ^ (row & 7);
    gload_lds16(A + (size_t)(row0 + row) * K + blk * 8, As[0] + c * 8);
  }
#pragma unroll
  for (int i = 0; i < 2; ++i) {
    const int c = tid + i * 256;
    const int row = c >> 3;
    const int blk = (c & 7) ^ (row & 7);
    gload_lds16(Bt + (size_t)(col0 + row) * K + blk * 8, Bs[0] + c * 8);
  }

  int cur = 0;
  for (int kt = 0; kt < K / 64; ++kt) {
    if (kt + 1 < K / 64) {
      const int ko = (kt + 1) * 64;
#pragma unroll
      for (int i = 0; i < 4; ++i) {
        const int c = tid + i * 256;
        const int row = c >> 3;
        const int blk = (c & 7) ^ (row & 7);
        gload_lds16(A + (size_t)(row0 + row) * K + ko + blk * 8, As[cur ^ 1] + c * 8);
      }
#pragma unroll
      for (int i = 0; i < 2; ++i) {
        const int c = tid + i * 256;
        const int row = c >> 3;
        const int blk = (c & 7) ^ (row & 7);
        gload_lds16(Bt + (size_t)(col0 + row) * K + ko + blk * 8, Bs[cur ^ 1] + c * 8);
      }
      asm volatile("s_waitcnt vmcnt(6)" ::: "memory");
    } else {
      asm volatile("s_waitcnt vmcnt(0)" ::: "memory");
    }
    __builtin_amdgcn_s_barrier();
    asm volatile("" ::: "memory");

    const u16* Ac = As[cur];
    const u16* Bc = Bs[cur];
#pragma unroll
    for (int ks = 0; ks < 2; ++ks) {
      short8 af[4], bf[NT];
      const int B = ks * 64 + g4 * 16;
      const int sw = (l15 & 7) << 4;
#pragma unroll
      for (int mt = 0; mt < 4; ++mt)
        af[mt] = *(const short8*)((const char*)Ac + (wm + mt * 16 + l15) * 128 + (B ^ sw));
#pragma unroll
      for (int nt = 0; nt < NT; ++nt)
        bf[nt] = *(const short8*)((const char*)Bc + (wn + nt * 16 + l15) * 128 + (B ^ sw));
#pragma unroll
      for (int mt = 0; mt < 4; ++mt)
#pragma unroll
        for (int nt = 0; nt < NT; ++nt)
          acc[mt][nt] = __builtin_amdgcn_mfma_f32_16x16x32_bf16(af[mt], bf[nt], acc[mt][nt], 0, 0, 0);
    }

    asm volatile("" ::: "memory");
    __builtin_amdgcn_s_barrier();
    cur ^= 1;
  }

#pragma unroll
  for (int nt = 0; nt < NT; ++nt) {
    const int col = col0 + wn + nt * 16 + l15;
    const float bv = bias[col];
    if (MODE == 0) {
      const int part = col >> 10;
      const int h = (col >> 6) & 15;
      const int d = col & 63;
      u16* dp = part == 0 ? qb : kb;
#pragma unroll
      for (int mt = 0; mt < 4; ++mt) {
        if (part == 2) {
          const int t0 = row0 + wm + mt * 16 + g4 * 4;
          const int bidx = t0 >> 11;
          const int tt = t0 & 2047;
          const unsigned lo = f2bf(acc[mt][nt][0] + bv) | ((unsigned)f2bf(acc[mt][nt][1] + bv) << 16);
          const unsigned hi = f2bf(acc[mt][nt][2] + bv) | ((unsigned)f2bf(acc[mt][nt][3] + bv) << 16);
          *(uint2*)&vb[((size_t)((bidx << 4) + h) * 64 + d) * 2048 + tt] = make_uint2(lo, hi);
        } else {
#pragma unroll
          for (int r = 0; r < 4; ++r) {
            const int row = row0 + wm + mt * 16 + g4 * 4 + r;
            const int bidx = row >> 11;
            const int tt = row & 2047;
            dp[((size_t)((bidx << 4) + h) * 2048 + tt) * 64 + d] = f2bf(acc[mt][nt][r] + bv);
          }
        }
      }
    } else {
#pragma unroll
      for (int mt = 0; mt < 4; ++mt) {
#pragma unroll
        for (int r = 0; r < 4; ++r) {
          const int row = row0 + wm + mt * 16 + g4 * 4 + r;
          outp[(size_t)row * NSIZE + col] = acc[mt][nt][r] + bv;
        }
      }
    }
  }
}

// -------- flash attention: paired q-tiles + split-kv, VALU diet (R18 body) --
// grid (32 bh, 24 y). LDS 40KB, launch_bounds (256,3) (NOT 4: R13 showed
// min-waves=4 clamps VGPR to 64 -> 58MB spill traffic, 1.7x slower).
__global__ __launch_bounds__(256, 3) void attn_fwd(const u16* __restrict__ Qb,
                                                   const u16* __restrict__ Kb,
                                                   const u16* __restrict__ Vtb,
                                                   u16* __restrict__ Yb,
                                                   char* __restrict__ pb) {
  __shared__ u16 Ks[2][64 * 64];
  __shared__ u16 Vs[2][64 * 64];
  __shared__ u16 Ps[4][1024];     // 2KB per wave, reused by both groups
  const int bh = blockIdx.x;
  const int y = blockIdx.y;
  int j, c0t, c1t, chunk, split;
  if (y < 8)       { j = 8 + y;  c0t = 0;  c1t = 15;        chunk = 0; split = 1; }
  else if (y < 16) { j = 15 - y; c0t = 0;  c1t = 2 * j + 1; chunk = 0; split = 0; }
  else             { j = y - 8;  c0t = 16; c1t = 2 * j + 1; chunk = 1; split = 1; }
  const int q0 = j * 128;
  const int tid = threadIdx.x;
  const int lane = tid & 63;
  const int wid = tid >> 6;
  const int l15 = lane & 15;
  const int g4 = lane >> 4;
  const size_t bhq = (size_t)bh * 2048 * 64;
  const u16* Kbase = Kb + bhq;
  const u16* Vbase = Vtb + bhq;  // [64 d][2048 t] per bh
  const float C2 = 0.18033688011112042f;  // 0.125 * log2(e)
  u16* Pw = &Ps[wid][0];
  const int wrow0 = q0 + wid * 32;       // wave's 32 q-rows

  short8 ones;
#pragma unroll
  for (int i = 0; i < 8; ++i) ones[i] = (short)0x3F80;  // bf16 1.0

  short8 qf[2][2];
#pragma unroll
  for (int g = 0; g < 2; ++g) {
    const u16* qp = Qb + bhq + (size_t)(wrow0 + g * 16 + l15) * 64 + g4 * 8;
    qf[g][0] = *(const short8*)(qp);
    qf[g][1] = *(const short8*)(qp + 32);
  }
  f32x4 accy[2][4] = {};
  float m_q[2] = {-1e30f, -1e30f};
  float m_r[2][4] = {{-1e30f, -1e30f, -1e30f, -1e30f}, {-1e30f, -1e30f, -1e30f, -1e30f}};
  float l_r[2][4] = {};

  int cur = 0;
#pragma unroll
  for (int cc = 0; cc < 2; ++cc) {
    const int c = tid + cc * 256;
    const int srow = c >> 3;
    const int sblk = (c & 7) ^ (srow & 7);
    gload_lds16(Kbase + (size_t)(c0t * 64 + srow) * 64 + sblk * 8, Ks[0] + c * 8);
    gload_lds16(Vbase + (size_t)srow * 2048 + c0t * 64 + sblk * 8, Vs[0] + c * 8);
  }

  for (int kv = c0t; kv <= c1t; ++kv) {
    const int kv0 = kv * 64;
    if (kv < c1t) {
      const int nx0 = kv0 + 64;
#pragma unroll
      for (int cc = 0; cc < 2; ++cc) {
        const int c = tid + cc * 256;
        const int srow = c >> 3;
        const int sblk = (c & 7) ^ (srow & 7);
        gload_lds16(Kbase + (size_t)(nx0 + srow) * 64 + sblk * 8, Ks[cur ^ 1] + c * 8);
        gload_lds16(Vbase + (size_t)srow * 2048 + nx0 + sblk * 8, Vs[cur ^ 1] + c * 8);
      }
      asm volatile("s_waitcnt vmcnt(4)" ::: "memory");
    } else {
      asm volatile("s_waitcnt vmcnt(0)" ::: "memory");
    }
    __builtin_amdgcn_s_barrier();
    asm volatile("" ::: "memory");

    if (kv0 <= wrow0 + 31) {   // wave-uniform skip of fully-masked tiles
      const u16* Kt = Ks[cur];
      const u16* Vt = Vs[cur];

      // ---- S^T = K Q^T, both groups, shared K fragments ----
      f32x4 s[2][4];
#pragma unroll
      for (int nt = 0; nt < 4; ++nt) {
        const int R = nt * 16 + l15;
        const int sw = (R & 7) << 4;
        short8 kf0 = *(const short8*)((const char*)Kt + R * 128 + ((g4 * 16) ^ sw));
        short8 kf1 = *(const short8*)((const char*)Kt + R * 128 + ((64 + g4 * 16) ^ sw));
        f32x4 z0 = __builtin_amdgcn_mfma_f32_16x16x32_bf16(kf0, qf[0][0], f32x4{}, 0, 0, 0);
        s[0][nt] = __builtin_amdgcn_mfma_f32_16x16x32_bf16(kf1, qf[0][1], z0, 0, 0, 0);
        f32x4 z1 = __builtin_amdgcn_mfma_f32_16x16x32_bf16(kf0, qf[1][0], f32x4{}, 0, 0, 0);
        s[1][nt] = __builtin_amdgcn_mfma_f32_16x16x32_bf16(kf1, qf[1][1], z1, 0, 0, 0);
      }

      // ---- per-group: mask, max (max3 chains), defer-max, exp, P round-trip --
      short8 pf[2][2];
#pragma unroll
      for (int g = 0; g < 2; ++g) {
        const int grow0 = wrow0 + g * 16;
        if (kv0 + 63 > grow0) {
          const int qg = grow0 + l15;
#pragma unroll
          for (int nt = 0; nt < 4; ++nt) {
            const int kbase = kv0 + nt * 16 + g4 * 4;
#pragma unroll
            for (int r = 0; r < 4; ++r)
              if (kbase + r > qg) s[g][nt][r] = -1e30f;
          }
        }
        // max3-friendly reduction chain over 16 values
        float mx = fmaxf(s[g][0][0], s[g][0][1]);
        mx = fmaxf(fmaxf(mx, s[g][0][2]), s[g][0][3]);
        mx = fmaxf(fmaxf(mx, s[g][1][0]), s[g][1][1]);
        mx = fmaxf(fmaxf(mx, s[g][1][2]), s[g][1][3]);
        mx = fmaxf(fmaxf(mx, s[g][2][0]), s[g][2][1]);
        mx = fmaxf(fmaxf(mx, s[g][2][2]), s[g][2][3]);
        mx = fmaxf(fmaxf(mx, s[g][3][0]), s[g][3][1]);
        mx = fmaxf(fmaxf(mx, s[g][3][2]), s[g][3][3]);
        mx = fmaxf(mx, __shfl_xor(mx, 16));
        mx = fmaxf(mx, __shfl_xor(mx, 32));
        if (!__all(mx <= m_q[g] + 44.0f)) {   // rescale path (rare, T13)
          m_q[g] = fmaxf(m_q[g], mx);
#pragma unroll
          for (int rr = 0; rr < 4; ++rr) {
            const float mn = __shfl(m_q[g], g4 * 4 + rr);
            const float al = __builtin_amdgcn_exp2f((m_r[g][rr] - mn) * C2);
            m_r[g][rr] = mn;
            l_r[g][rr] *= al;
#pragma unroll
            for (int nt = 0; nt < 4; ++nt) accy[g][nt][rr] *= al;
          }
        }
        const float m2 = m_q[g] * C2;
#pragma unroll
        for (int nt = 0; nt < 4; ++nt)
#pragma unroll
          for (int r = 0; r < 4; ++r)
            s[g][nt][r] = __builtin_amdgcn_exp2f(fmaf(s[g][nt][r], C2, -m2));

        // P -> per-wave LDS (HW cvt_pk packing, b64 swizzled), then read frags
#pragma unroll
        for (int nt = 0; nt < 4; ++nt) {
          const unsigned lo = cvt_pk_bf16(s[g][nt][0], s[g][nt][1]);
          const unsigned hi = cvt_pk_bf16(s[g][nt][2], s[g][nt][3]);
          const int colB = nt * 32 + g4 * 8;
          *(uint2*)((char*)Pw + l15 * 128 + (colB ^ ((l15 & 7) << 4))) = make_uint2(lo, hi);
        }
        {
          const int sw = (l15 & 7) << 4;
          pf[g][0] = *(const short8*)((const char*)Pw + l15 * 128 + ((g4 * 16) ^ sw));
          pf[g][1] = *(const short8*)((const char*)Pw + l15 * 128 + ((64 + g4 * 16) ^ sw));
        }
      }

      // ---- psum via ones-MFMA, PV with shared V fragments ----
#pragma unroll
      for (int g = 0; g < 2; ++g) {
        f32x4 ps = __builtin_amdgcn_mfma_f32_16x16x32_bf16(pf[g][0], ones, f32x4{}, 0, 0, 0);
        ps = __builtin_amdgcn_mfma_f32_16x16x32_bf16(pf[g][1], ones, ps, 0, 0, 0);
#pragma unroll
        for (int rr = 0; rr < 4; ++rr) l_r[g][rr] += ps[rr];
      }
#pragma unroll
      for (int nt = 0; nt < 4; ++nt) {
        const int R = nt * 16 + l15;
        const int sw = (R & 7) << 4;
        short8 vf0 = *(const short8*)((const char*)Vt + R * 128 + ((g4 * 16) ^ sw));
        short8 vf1 = *(const short8*)((const char*)Vt + R * 128 + ((64 + g4 * 16) ^ sw));
#pragma unroll
        for (int g = 0; g < 2; ++g) {
          accy[g][nt] = __builtin_amdgcn_mfma_f32_16x16x32_bf16(pf[g][0], vf0, accy[g][nt], 0, 0, 0);
          accy[g][nt] = __builtin_amdgcn_mfma_f32_16x16x32_bf16(pf[g][1], vf1, accy[g][nt], 0, 0, 0);
        }
      }
    }

    asm volatile("" ::: "memory");
    __builtin_amdgcn_s_barrier();
    cur ^= 1;
  }

  if (!split) {
#pragma unroll
    for (int g = 0; g < 2; ++g)
#pragma unroll
      for (int r = 0; r < 4; ++r) {
        const int row = wrow0 + g * 16 + g4 * 4 + r;
        const float inv = 1.0f / l_r[g][r];
        const size_t base = ((size_t)(bh >> 4) * 2048 + row) * 1024 + (bh & 15) * 64;
#pragma unroll
        for (int nt = 0; nt < 4; ++nt)
          Yb[base + nt * 16 + l15] = f2bf(accy[g][nt][r] * inv);
      }
  } else {
    char* slot = pb + ((size_t)(bh * 8 + (j - 8)) * 2 + chunk) * 17408;
    u16* O = (u16*)slot;
    float* mf = (float*)(slot + 16384);
    float* lf = (float*)(slot + 16896);
#pragma unroll
    for (int g = 0; g < 2; ++g)
#pragma unroll
      for (int r = 0; r < 4; ++r) {
        const int row = wid * 32 + g * 16 + g4 * 4 + r;   // local 0..127
        const float inv = 1.0f / l_r[g][r];
#pragma unroll
        for (int nt = 0; nt < 4; ++nt)
          O[row * 64 + nt * 16 + l15] = f2bf(accy[g][nt][r] * inv);
        if (l15 == 0) { mf[row] = m_r[g][r]; lf[row] = l_r[g][r]; }
      }
  }
}

// -------- combine split-kv partials --------
__global__ __launch_bounds__(256) void attn_combine(const char* __restrict__ pb,
                                                    u16* __restrict__ Yb) {
  const int x = blockIdx.x;        // 0..15
  const int bh = blockIdx.y;
  const int j = 8 + (x >> 1);
  const int half = x & 1;
  const int T = 2 * j + half;
  const char* s0 = pb + ((size_t)(bh * 8 + (j - 8)) * 2) * 17408;
  const char* s1 = s0 + 17408;
  const int tid = threadIdx.x;
  const int r64 = tid >> 2;        // 0..63
  const int rowl = half * 64 + r64;
  const int dc = (tid & 3) * 16;   // 0,16,32,48
  const float C2 = 0.18033688011112042f;
  const float m0 = ((const float*)(s0 + 16384))[rowl];
  const float m1 = ((const float*)(s1 + 16384))[rowl];
  const float l0 = ((const float*)(s0 + 16896))[rowl];
  const float l1 = ((const float*)(s1 + 16896))[rowl];
  const float m = fmaxf(m0, m1);
  const float w0 = __builtin_amdgcn_exp2f((m0 - m) * C2) * l0;
  const float w1 = __builtin_amdgcn_exp2f((m1 - m) * C2) * l1;
  const float inv = 1.0f / (w0 + w1);
  const float a0 = w0 * inv, a1 = w1 * inv;
  const u16* O0 = (const u16*)s0 + rowl * 64 + dc;
  const u16* O1 = (const u16*)s1 + rowl * 64 + dc;
  const int qrow = T * 64 + r64;
  u16* yp = Yb + ((size_t)(bh >> 4) * 2048 + qrow) * 1024 + (bh & 15) * 64 + dc;
  union { uint4 v; u16 h[8]; } a[2], b[2], o[2];
  a[0].v = *(const uint4*)O0; a[1].v = *(const uint4*)(O0 + 8);
  b[0].v = *(const uint4*)O1; b[1].v = *(const uint4*)(O1 + 8);
#pragma unroll
  for (int jj = 0; jj < 2; ++jj)
#pragma unroll
    for (int i = 0; i < 8; ++i)
      o[jj].h[i] = f2bf(bf2f(a[jj].h[i]) * a0 + bf2f(b[jj].h[i]) * a1);
  *(uint4*)yp = o[0].v;
  *(uint4*)(yp + 8) = o[1].v;
}

extern "C" void kernel_launch(void* const* d_in, const int* in_sizes, int n_in,
                              void* d_out, int out_size, void* d_ws, size_t ws_size,
                              hipStream_t stream) {
  const float* x      = (const float*)d_in[0];
  const float* w_attn = (const float*)d_in[1];
  const float* b_attn = (const float*)d_in[2];
  const float* w_proj = (const float*)d_in[3];
  const float* b_proj = (const float*)d_in[4];
  float* out = (float*)d_out;
  char* ws = (char*)d_ws;

  u16* xb  = (u16*)(ws + (size_t)0);           // 8 MB: x bf16 [4096][1024]
  u16* wTa = (u16*)(ws + ((size_t)8  << 20));  // 6 MB: w_attn^T bf16 [3072][1024]
  u16* wTp = (u16*)(ws + ((size_t)14 << 20));  // 2 MB: w_proj^T bf16 [1024][1024]
  u16* qb  = (u16*)(ws + ((size_t)16 << 20));  // 8 MB: Q [32][2048][64]
  u16* kb  = (u16*)(ws + ((size_t)24 << 20));  // 8 MB: K [32][2048][64]
  u16* vb  = (u16*)(ws + ((size_t)32 << 20));  // 8 MB: V^T [32][64][2048]
  u16* yb  = (u16*)(ws + ((size_t)40 << 20));  // 8 MB: y bf16 [4096][1024]
  char* pb = ws;   // split-kv partials overlay xb+wTa (dead after QKV GEMM)

  fused_prologue<<<3072, 256, 0, stream>>>(x, w_attn, w_proj, xb, wTa, wTp);
  gemm_bt<3072, 0, 64><<<dim3(32, 48), 256, 0, stream>>>(xb, wTa, b_attn, qb, kb, vb, nullptr);
  attn_fwd<<<dim3(32, 24), 256, 0, stream>>>(qb, kb, vb, yb, pb);
  attn_combine<<<dim3(16, 32), 256, 0, stream>>>(pb, yb);
  gemm_bt<1024, 1, 64><<<dim3(32, 16), 256, 0, stream>>>(yb, wTp, b_proj, nullptr, nullptr, nullptr, out);
}

// Round 21
// 101.842 us; speedup vs baseline: 1.0442x; 1.0042x over previous
//
#include <hip/hip_runtime.h>
#include <hip/hip_bf16.h>
#include <math.h>

typedef __attribute__((ext_vector_type(8))) short short8;
typedef __attribute__((ext_vector_type(4))) float f32x4;
typedef unsigned short u16;

static __device__ __forceinline__ u16 f2bf(float f) {
  union { float f; unsigned u; } v; v.f = f;
  unsigned r = v.u + 0x7fffu + ((v.u >> 16) & 1u);
  return (u16)(r >> 16);
}

static __device__ __forceinline__ float bf2f(u16 h) {
  union { unsigned u; float f; } v; v.u = ((unsigned)h) << 16;
  return v.f;
}

// gfx950 HW packed f32->bf16 convert (no builtin; inline asm per T12)
static __device__ __forceinline__ unsigned cvt_pk_bf16(float lo, float hi) {
  unsigned r;
  asm("v_cvt_pk_bf16_f32 %0, %1, %2" : "=v"(r) : "v"(lo), "v"(hi));
  return r;
}

static __device__ __forceinline__ void gload_lds16(const void* g, void* l) {
  __builtin_amdgcn_global_load_lds(
      (const __attribute__((address_space(1))) void*)g,
      (__attribute__((address_space(3))) void*)l, 16, 0, 0);
}

// -------- fused prologue: cvt x -> bf16 | transpose w_attn | transpose w_proj --
__device__ __forceinline__ void transpose_tile(const float* __restrict__ W,
                                               u16* __restrict__ WT,
                                               int ND, int KD, int c0, int k0,
                                               float (*tile)[65], int t) {
  const int lr = t >> 2;
  const int lc = (t & 3) * 16;
  const float* src = W + (size_t)(k0 + lr) * ND + c0 + lc;
#pragma unroll
  for (int i = 0; i < 16; i += 4) {
    float4 v = *(const float4*)(src + i);
    tile[lr][lc + i] = v.x; tile[lr][lc + i + 1] = v.y;
    tile[lr][lc + i + 2] = v.z; tile[lr][lc + i + 3] = v.w;
  }
  __syncthreads();
  unsigned pk[8];
#pragma unroll
  for (int j = 0; j < 8; ++j) {
    u16 lo = f2bf(tile[lc + 2 * j][lr]);
    u16 hi = f2bf(tile[lc + 2 * j + 1][lr]);
    pk[j] = lo | ((unsigned)hi << 16);
  }
  u16* dst = WT + (size_t)(c0 + lr) * KD + k0 + lc;
  *(uint4*)(dst) = make_uint4(pk[0], pk[1], pk[2], pk[3]);
  *(uint4*)(dst + 8) = make_uint4(pk[4], pk[5], pk[6], pk[7]);
}

__global__ __launch_bounds__(256) void fused_prologue(const float* __restrict__ x,
                                                      const float* __restrict__ w_attn,
                                                      const float* __restrict__ w_proj,
                                                      u16* __restrict__ xb,
                                                      u16* __restrict__ wTa,
                                                      u16* __restrict__ wTp) {
  __shared__ float tile[64][65];
  const int b = blockIdx.x;
  const int t = threadIdx.x;
  if (b < 2048) {
    const int i = (b * 256 + t) * 8;
    float4 a = *(const float4*)(x + i);
    float4 c = *(const float4*)(x + i + 4);
    uint4 pk;
    pk.x = f2bf(a.x) | ((unsigned)f2bf(a.y) << 16);
    pk.y = f2bf(a.z) | ((unsigned)f2bf(a.w) << 16);
    pk.z = f2bf(c.x) | ((unsigned)f2bf(c.y) << 16);
    pk.w = f2bf(c.z) | ((unsigned)f2bf(c.w) << 16);
    *(uint4*)(xb + i) = pk;
  } else if (b < 2816) {
    const int id = b - 2048;
    transpose_tile(w_attn, wTa, 3072, 1024, (id % 48) * 64, (id / 48) * 64, tile, t);
  } else {
    const int id = b - 2816;
    transpose_tile(w_proj, wTp, 1024, 1024, (id % 16) * 64, (id / 16) * 64, tile, t);
  }
}

// -------- GEMM: C[M,N] = A[M,1024] * Bt[N,1024]^T + bias (R18, unchanged) ----
// Tile 128x64, BK=64, double-buffered counted-vmcnt (T4). LDS 48KB -> 3/CU.
// XOR swizzle (c&7)^(row&7) both-sides (conflict-free, R10-verified).
template<int NSIZE, int MODE, int BN>
__global__ __launch_bounds__(256) void gemm_bt(const u16* __restrict__ A,
                                               const u16* __restrict__ Bt,
                                               const float* __restrict__ bias,
                                               u16* __restrict__ qb,
                                               u16* __restrict__ kb,
                                               u16* __restrict__ vb,
                                               float* __restrict__ outp) {
  constexpr int K = 1024;
  constexpr int NT = BN / 32;          // 2
  static_assert(BN == 64, "vmcnt literal assumes BN=64");
  __shared__ u16 As[2][128 * 64];
  __shared__ u16 Bs[2][64 * 64];
  const int tid = threadIdx.x;
  const int lane = tid & 63;
  const int wid = tid >> 6;
  const int l15 = lane & 15;
  const int g4 = lane >> 4;
  const int wm = (wid >> 1) * 64;
  const int wn = (wid & 1) * 32;
  const int row0 = blockIdx.x * 128;
  const int col0 = blockIdx.y * BN;

  f32x4 acc[4][NT] = {};

#pragma unroll
  for (int i = 0; i < 4; ++i) {
    const int c = tid + i * 256;
    const int row = c >> 3;
    const int blk = (c & 7) ^ (row & 7);
    gload_lds16(A + (size_t)(row0 + row) * K + blk * 8, As[0] + c * 8);
  }
#pragma unroll
  for (int i = 0; i < 2; ++i) {
    const int c = tid + i * 256;
    const int row = c >> 3;
    const int blk = (c & 7) ^ (row & 7);
    gload_lds16(Bt + (size_t)(col0 + row) * K + blk * 8, Bs[0] + c * 8);
  }

  int cur = 0;
  for (int kt = 0; kt < K / 64; ++kt) {
    if (kt + 1 < K / 64) {
      const int ko = (kt + 1) * 64;
#pragma unroll
      for (int i = 0; i < 4; ++i) {
        const int c = tid + i * 256;
        const int row = c >> 3;
        const int blk = (c & 7) ^ (row & 7);
        gload_lds16(A + (size_t)(row0 + row) * K + ko + blk * 8, As[cur ^ 1] + c * 8);
      }
#pragma unroll
      for (int i = 0; i < 2; ++i) {
        const int c = tid + i * 256;
        const int row = c >> 3;
        const int blk = (c & 7) ^ (row & 7);
        gload_lds16(Bt + (size_t)(col0 + row) * K + ko + blk * 8, Bs[cur ^ 1] + c * 8);
      }
      asm volatile("s_waitcnt vmcnt(6)" ::: "memory");
    } else {
      asm volatile("s_waitcnt vmcnt(0)" ::: "memory");
    }
    __builtin_amdgcn_s_barrier();
    asm volatile("" ::: "memory");

    const u16* Ac = As[cur];
    const u16* Bc = Bs[cur];
#pragma unroll
    for (int ks = 0; ks < 2; ++ks) {
      short8 af[4], bf[NT];
      const int B = ks * 64 + g4 * 16;
      const int sw = (l15 & 7) << 4;
#pragma unroll
      for (int mt = 0; mt < 4; ++mt)
        af[mt] = *(const short8*)((const char*)Ac + (wm + mt * 16 + l15) * 128 + (B ^ sw));
#pragma unroll
      for (int nt = 0; nt < NT; ++nt)
        bf[nt] = *(const short8*)((const char*)Bc + (wn + nt * 16 + l15) * 128 + (B ^ sw));
#pragma unroll
      for (int mt = 0; mt < 4; ++mt)
#pragma unroll
        for (int nt = 0; nt < NT; ++nt)
          acc[mt][nt] = __builtin_amdgcn_mfma_f32_16x16x32_bf16(af[mt], bf[nt], acc[mt][nt], 0, 0, 0);
    }

    asm volatile("" ::: "memory");
    __builtin_amdgcn_s_barrier();
    cur ^= 1;
  }

#pragma unroll
  for (int nt = 0; nt < NT; ++nt) {
    const int col = col0 + wn + nt * 16 + l15;
    const float bv = bias[col];
    if (MODE == 0) {
      const int part = col >> 10;
      const int h = (col >> 6) & 15;
      const int d = col & 63;
      u16* dp = part == 0 ? qb : kb;
#pragma unroll
      for (int mt = 0; mt < 4; ++mt) {
        if (part == 2) {
          const int t0 = row0 + wm + mt * 16 + g4 * 4;
          const int bidx = t0 >> 11;
          const int tt = t0 & 2047;
          const unsigned lo = f2bf(acc[mt][nt][0] + bv) | ((unsigned)f2bf(acc[mt][nt][1] + bv) << 16);
          const unsigned hi = f2bf(acc[mt][nt][2] + bv) | ((unsigned)f2bf(acc[mt][nt][3] + bv) << 16);
          *(uint2*)&vb[((size_t)((bidx << 4) + h) * 64 + d) * 2048 + tt] = make_uint2(lo, hi);
        } else {
#pragma unroll
          for (int r = 0; r < 4; ++r) {
            const int row = row0 + wm + mt * 16 + g4 * 4 + r;
            const int bidx = row >> 11;
            const int tt = row & 2047;
            dp[((size_t)((bidx << 4) + h) * 2048 + tt) * 64 + d] = f2bf(acc[mt][nt][r] + bv);
          }
        }
      }
    } else {
#pragma unroll
      for (int mt = 0; mt < 4; ++mt) {
#pragma unroll
        for (int r = 0; r < 4; ++r) {
          const int row = row0 + wm + mt * 16 + g4 * 4 + r;
          outp[(size_t)row * NSIZE + col] = acc[mt][nt][r] + bv;
        }
      }
    }
  }
}

// -------- flash attention: R18 body + T5 setprio + per-group P buffers ------
// grid (32 bh, 24 y). LDS 44KB (3 blocks/CU), launch_bounds (256,3)
// (NOT 4: R13 showed min-waves=4 clamps VGPR to 64 -> spill disaster).
// setprio(1) around MFMA clusters (m191: +4-7% on attn, phase-diverse blocks).
// Per-group P buffers remove the group0-read -> group1-write WAR hazard.
__global__ __launch_bounds__(256, 3) void attn_fwd(const u16* __restrict__ Qb,
                                                   const u16* __restrict__ Kb,
                                                   const u16* __restrict__ Vtb,
                                                   u16* __restrict__ Yb,
                                                   char* __restrict__ pb) {
  __shared__ u16 Ks[2][64 * 64];
  __shared__ u16 Vs[2][64 * 64];
  __shared__ u16 Ps[4][2][1024];  // per-wave, per-group 2KB
  const int bh = blockIdx.x;
  const int y = blockIdx.y;
  int j, c0t, c1t, chunk, split;
  if (y < 8)       { j = 8 + y;  c0t = 0;  c1t = 15;        chunk = 0; split = 1; }
  else if (y < 16) { j = 15 - y; c0t = 0;  c1t = 2 * j + 1; chunk = 0; split = 0; }
  else             { j = y - 8;  c0t = 16; c1t = 2 * j + 1; chunk = 1; split = 1; }
  const int q0 = j * 128;
  const int tid = threadIdx.x;
  const int lane = tid & 63;
  const int wid = tid >> 6;
  const int l15 = lane & 15;
  const int g4 = lane >> 4;
  const size_t bhq = (size_t)bh * 2048 * 64;
  const u16* Kbase = Kb + bhq;
  const u16* Vbase = Vtb + bhq;  // [64 d][2048 t] per bh
  const float C2 = 0.18033688011112042f;  // 0.125 * log2(e)
  const int wrow0 = q0 + wid * 32;       // wave's 32 q-rows

  short8 ones;
#pragma unroll
  for (int i = 0; i < 8; ++i) ones[i] = (short)0x3F80;  // bf16 1.0

  short8 qf[2][2];
#pragma unroll
  for (int g = 0; g < 2; ++g) {
    const u16* qp = Qb + bhq + (size_t)(wrow0 + g * 16 + l15) * 64 + g4 * 8;
    qf[g][0] = *(const short8*)(qp);
    qf[g][1] = *(const short8*)(qp + 32);
  }
  f32x4 accy[2][4] = {};
  float m_q[2] = {-1e30f, -1e30f};
  float m_r[2][4] = {{-1e30f, -1e30f, -1e30f, -1e30f}, {-1e30f, -1e30f, -1e30f, -1e30f}};
  float l_r[2][4] = {};

  int cur = 0;
#pragma unroll
  for (int cc = 0; cc < 2; ++cc) {
    const int c = tid + cc * 256;
    const int srow = c >> 3;
    const int sblk = (c & 7) ^ (srow & 7);
    gload_lds16(Kbase + (size_t)(c0t * 64 + srow) * 64 + sblk * 8, Ks[0] + c * 8);
    gload_lds16(Vbase + (size_t)srow * 2048 + c0t * 64 + sblk * 8, Vs[0] + c * 8);
  }

  for (int kv = c0t; kv <= c1t; ++kv) {
    const int kv0 = kv * 64;
    if (kv < c1t) {
      const int nx0 = kv0 + 64;
#pragma unroll
      for (int cc = 0; cc < 2; ++cc) {
        const int c = tid + cc * 256;
        const int srow = c >> 3;
        const int sblk = (c & 7) ^ (srow & 7);
        gload_lds16(Kbase + (size_t)(nx0 + srow) * 64 + sblk * 8, Ks[cur ^ 1] + c * 8);
        gload_lds16(Vbase + (size_t)srow * 2048 + nx0 + sblk * 8, Vs[cur ^ 1] + c * 8);
      }
      asm volatile("s_waitcnt vmcnt(4)" ::: "memory");
    } else {
      asm volatile("s_waitcnt vmcnt(0)" ::: "memory");
    }
    __builtin_amdgcn_s_barrier();
    asm volatile("" ::: "memory");

    if (kv0 <= wrow0 + 31) {   // wave-uniform skip of fully-masked tiles
      const u16* Kt = Ks[cur];
      const u16* Vt = Vs[cur];

      // ---- S^T = K Q^T, both groups, shared K fragments (T5 setprio) ----
      f32x4 s[2][4];
      __builtin_amdgcn_s_setprio(1);
#pragma unroll
      for (int nt = 0; nt < 4; ++nt) {
        const int R = nt * 16 + l15;
        const int sw = (R & 7) << 4;
        short8 kf0 = *(const short8*)((const char*)Kt + R * 128 + ((g4 * 16) ^ sw));
        short8 kf1 = *(const short8*)((const char*)Kt + R * 128 + ((64 + g4 * 16) ^ sw));
        f32x4 z0 = __builtin_amdgcn_mfma_f32_16x16x32_bf16(kf0, qf[0][0], f32x4{}, 0, 0, 0);
        s[0][nt] = __builtin_amdgcn_mfma_f32_16x16x32_bf16(kf1, qf[0][1], z0, 0, 0, 0);
        f32x4 z1 = __builtin_amdgcn_mfma_f32_16x16x32_bf16(kf0, qf[1][0], f32x4{}, 0, 0, 0);
        s[1][nt] = __builtin_amdgcn_mfma_f32_16x16x32_bf16(kf1, qf[1][1], z1, 0, 0, 0);
      }
      __builtin_amdgcn_s_setprio(0);

      // ---- per-group: mask, max (max3 chains), defer-max, exp, P round-trip --
      short8 pf[2][2];
#pragma unroll
      for (int g = 0; g < 2; ++g) {
        char* PwG = (char*)&Ps[wid][g][0];
        const int grow0 = wrow0 + g * 16;
        if (kv0 + 63 > grow0) {
          const int qg = grow0 + l15;
#pragma unroll
          for (int nt = 0; nt < 4; ++nt) {
            const int kbase = kv0 + nt * 16 + g4 * 4;
#pragma unroll
            for (int r = 0; r < 4; ++r)
              if (kbase + r > qg) s[g][nt][r] = -1e30f;
          }
        }
        // max3-friendly reduction chain over 16 values
        float mx = fmaxf(s[g][0][0], s[g][0][1]);
        mx = fmaxf(fmaxf(mx, s[g][0][2]), s[g][0][3]);
        mx = fmaxf(fmaxf(mx, s[g][1][0]), s[g][1][1]);
        mx = fmaxf(fmaxf(mx, s[g][1][2]), s[g][1][3]);
        mx = fmaxf(fmaxf(mx, s[g][2][0]), s[g][2][1]);
        mx = fmaxf(fmaxf(mx, s[g][2][2]), s[g][2][3]);
        mx = fmaxf(fmaxf(mx, s[g][3][0]), s[g][3][1]);
        mx = fmaxf(fmaxf(mx, s[g][3][2]), s[g][3][3]);
        mx = fmaxf(mx, __shfl_xor(mx, 16));
        mx = fmaxf(mx, __shfl_xor(mx, 32));
        if (!__all(mx <= m_q[g] + 44.0f)) {   // rescale path (rare, T13)
          m_q[g] = fmaxf(m_q[g], mx);
#pragma unroll
          for (int rr = 0; rr < 4; ++rr) {
            const float mn = __shfl(m_q[g], g4 * 4 + rr);
            const float al = __builtin_amdgcn_exp2f((m_r[g][rr] - mn) * C2);
            m_r[g][rr] = mn;
            l_r[g][rr] *= al;
#pragma unroll
            for (int nt = 0; nt < 4; ++nt) accy[g][nt][rr] *= al;
          }
        }
        const float m2 = m_q[g] * C2;
#pragma unroll
        for (int nt = 0; nt < 4; ++nt)
#pragma unroll
          for (int r = 0; r < 4; ++r)
            s[g][nt][r] = __builtin_amdgcn_exp2f(fmaf(s[g][nt][r], C2, -m2));

        // P -> per-wave per-group LDS (HW cvt_pk, b64 swizzled), read frags
#pragma unroll
        for (int nt = 0; nt < 4; ++nt) {
          const unsigned lo = cvt_pk_bf16(s[g][nt][0], s[g][nt][1]);
          const unsigned hi = cvt_pk_bf16(s[g][nt][2], s[g][nt][3]);
          const int colB = nt * 32 + g4 * 8;
          *(uint2*)(PwG + l15 * 128 + (colB ^ ((l15 & 7) << 4))) = make_uint2(lo, hi);
        }
        {
          const int sw = (l15 & 7) << 4;
          pf[g][0] = *(const short8*)(PwG + l15 * 128 + ((g4 * 16) ^ sw));
          pf[g][1] = *(const short8*)(PwG + l15 * 128 + ((64 + g4 * 16) ^ sw));
        }
      }

      // ---- psum via ones-MFMA, PV with shared V fragments (T5 setprio) ----
      __builtin_amdgcn_s_setprio(1);
#pragma unroll
      for (int g = 0; g < 2; ++g) {
        f32x4 ps = __builtin_amdgcn_mfma_f32_16x16x32_bf16(pf[g][0], ones, f32x4{}, 0, 0, 0);
        ps = __builtin_amdgcn_mfma_f32_16x16x32_bf16(pf[g][1], ones, ps, 0, 0, 0);
#pragma unroll
        for (int rr = 0; rr < 4; ++rr) l_r[g][rr] += ps[rr];
      }
#pragma unroll
      for (int nt = 0; nt < 4; ++nt) {
        const int R = nt * 16 + l15;
        const int sw = (R & 7) << 4;
        short8 vf0 = *(const short8*)((const char*)Vt + R * 128 + ((g4 * 16) ^ sw));
        short8 vf1 = *(const short8*)((const char*)Vt + R * 128 + ((64 + g4 * 16) ^ sw));
#pragma unroll
        for (int g = 0; g < 2; ++g) {
          accy[g][nt] = __builtin_amdgcn_mfma_f32_16x16x32_bf16(pf[g][0], vf0, accy[g][nt], 0, 0, 0);
          accy[g][nt] = __builtin_amdgcn_mfma_f32_16x16x32_bf16(pf[g][1], vf1, accy[g][nt], 0, 0, 0);
        }
      }
      __builtin_amdgcn_s_setprio(0);
    }

    asm volatile("" ::: "memory");
    __builtin_amdgcn_s_barrier();
    cur ^= 1;
  }

  if (!split) {
#pragma unroll
    for (int g = 0; g < 2; ++g)
#pragma unroll
      for (int r = 0; r < 4; ++r) {
        const int row = wrow0 + g * 16 + g4 * 4 + r;
        const float inv = 1.0f / l_r[g][r];
        const size_t base = ((size_t)(bh >> 4) * 2048 + row) * 1024 + (bh & 15) * 64;
#pragma unroll
        for (int nt = 0; nt < 4; ++nt)
          Yb[base + nt * 16 + l15] = f2bf(accy[g][nt][r] * inv);
      }
  } else {
    char* slot = pb + ((size_t)(bh * 8 + (j - 8)) * 2 + chunk) * 17408;
    u16* O = (u16*)slot;
    float* mf = (float*)(slot + 16384);
    float* lf = (float*)(slot + 16896);
#pragma unroll
    for (int g = 0; g < 2; ++g)
#pragma unroll
      for (int r = 0; r < 4; ++r) {
        const int row = wid * 32 + g * 16 + g4 * 4 + r;   // local 0..127
        const float inv = 1.0f / l_r[g][r];
#pragma unroll
        for (int nt = 0; nt < 4; ++nt)
          O[row * 64 + nt * 16 + l15] = f2bf(accy[g][nt][r] * inv);
        if (l15 == 0) { mf[row] = m_r[g][r]; lf[row] = l_r[g][r]; }
      }
  }
}

// -------- combine split-kv partials --------
__global__ __launch_bounds__(256) void attn_combine(const char* __restrict__ pb,
                                                    u16* __restrict__ Yb) {
  const int x = blockIdx.x;        // 0..15
  const int bh = blockIdx.y;
  const int j = 8 + (x >> 1);
  const int half = x & 1;
  const int T = 2 * j + half;
  const char* s0 = pb + ((size_t)(bh * 8 + (j - 8)) * 2) * 17408;
  const char* s1 = s0 + 17408;
  const int tid = threadIdx.x;
  const int r64 = tid >> 2;        // 0..63
  const int rowl = half * 64 + r64;
  const int dc = (tid & 3) * 16;   // 0,16,32,48
  const float C2 = 0.18033688011112042f;
  const float m0 = ((const float*)(s0 + 16384))[rowl];
  const float m1 = ((const float*)(s1 + 16384))[rowl];
  const float l0 = ((const float*)(s0 + 16896))[rowl];
  const float l1 = ((const float*)(s1 + 16896))[rowl];
  const float m = fmaxf(m0, m1);
  const float w0 = __builtin_amdgcn_exp2f((m0 - m) * C2) * l0;
  const float w1 = __builtin_amdgcn_exp2f((m1 - m) * C2) * l1;
  const float inv = 1.0f / (w0 + w1);
  const float a0 = w0 * inv, a1 = w1 * inv;
  const u16* O0 = (const u16*)s0 + rowl * 64 + dc;
  const u16* O1 = (const u16*)s1 + rowl * 64 + dc;
  const int qrow = T * 64 + r64;
  u16* yp = Yb + ((size_t)(bh >> 4) * 2048 + qrow) * 1024 + (bh & 15) * 64 + dc;
  union { uint4 v; u16 h[8]; } a[2], b[2], o[2];
  a[0].v = *(const uint4*)O0; a[1].v = *(const uint4*)(O0 + 8);
  b[0].v = *(const uint4*)O1; b[1].v = *(const uint4*)(O1 + 8);
#pragma unroll
  for (int jj = 0; jj < 2; ++jj)
#pragma unroll
    for (int i = 0; i < 8; ++i)
      o[jj].h[i] = f2bf(bf2f(a[jj].h[i]) * a0 + bf2f(b[jj].h[i]) * a1);
  *(uint4*)yp = o[0].v;
  *(uint4*)(yp + 8) = o[1].v;
}

extern "C" void kernel_launch(void* const* d_in, const int* in_sizes, int n_in,
                              void* d_out, int out_size, void* d_ws, size_t ws_size,
                              hipStream_t stream) {
  const float* x      = (const float*)d_in[0];
  const float* w_attn = (const float*)d_in[1];
  const float* b_attn = (const float*)d_in[2];
  const float* w_proj = (const float*)d_in[3];
  const float* b_proj = (const float*)d_in[4];
  float* out = (float*)d_out;
  char* ws = (char*)d_ws;

  u16* xb  = (u16*)(ws + (size_t)0);           // 8 MB: x bf16 [4096][1024]
  u16* wTa = (u16*)(ws + ((size_t)8  << 20));  // 6 MB: w_attn^T bf16 [3072][1024]
  u16* wTp = (u16*)(ws + ((size_t)14 << 20));  // 2 MB: w_proj^T bf16 [1024][1024]
  u16* qb  = (u16*)(ws + ((size_t)16 << 20));  // 8 MB: Q [32][2048][64]
  u16* kb  = (u16*)(ws + ((size_t)24 << 20));  // 8 MB: K [32][2048][64]
  u16* vb  = (u16*)(ws + ((size_t)32 << 20));  // 8 MB: V^T [32][64][2048]
  u16* yb  = (u16*)(ws + ((size_t)40 << 20));  // 8 MB: y bf16 [4096][1024]
  char* pb = ws;   // split-kv partials overlay xb+wTa (dead after QKV GEMM)

  fused_prologue<<<3072, 256, 0, stream>>>(x, w_attn, w_proj, xb, wTa, wTp);
  gemm_bt<3072, 0, 64><<<dim3(32, 48), 256, 0, stream>>>(xb, wTa, b_attn, qb, kb, vb, nullptr);
  attn_fwd<<<dim3(32, 24), 256, 0, stream>>>(qb, kb, vb, yb, pb);
  attn_combine<<<dim3(16, 32), 256, 0, stream>>>(pb, yb);
  gemm_bt<1024, 1, 64><<<dim3(32, 16), 256, 0, stream>>>(yb, wTp, b_proj, nullptr, nullptr, nullptr, out);
}